// Round 1
// baseline (20800.896 us; speedup 1.0000x reference)
//
#include <hip/hip_runtime.h>

// Problem constants
constexpr int B_ = 256;
constexpr int T_ = 128;
constexpr int F_ = 32;
constexpr int U_ = 512;   // U_ENC
constexpr int D_ = 512;
constexpr int A_ = 512;
constexpr int G_ = 2048;  // 4*D

__device__ __forceinline__ float sigf(float x) { return 1.0f / (1.0f + __expf(-x)); }
__device__ __forceinline__ float tanh_fast(float x) {
    return 2.0f / (1.0f + __expf(-2.0f * x)) - 1.0f;
}

// ---------------------------------------------------------------------------
// enc_proj[r][a] = sum_u enc[r][u] * Wk[u][a];  r = b*T + t  (M=32768,K=512,N=512)
// BM=32, BN=64, BK=32, 256 threads (16x16), TM=2, TN=4. grid (N/64, M/32)
__global__ __launch_bounds__(256) void k_encproj(const float* __restrict__ enc,
                                                 const float* __restrict__ Wk,
                                                 float* __restrict__ ep) {
    __shared__ float As[32][34];  // [k][m] padded
    __shared__ float Bs[32][64];  // [k][n]
    const int n0 = blockIdx.x * 64;
    const int m0 = blockIdx.y * 32;
    const int tid = threadIdx.x;
    const int tx = tid & 15, ty = tid >> 4;
    float acc[2][4] = {};
    for (int k0 = 0; k0 < U_; k0 += 32) {
        {   // A tile: 32x32 -> 256 float4, 1/thread, store transposed
            int m = tid >> 3, k4 = (tid & 7) * 4;
            float4 v = *(const float4*)(enc + (size_t)(m0 + m) * U_ + k0 + k4);
            As[k4 + 0][m] = v.x; As[k4 + 1][m] = v.y; As[k4 + 2][m] = v.z; As[k4 + 3][m] = v.w;
        }
        #pragma unroll
        for (int p = 0; p < 2; ++p) {  // B tile: 32x64 -> 512 float4, 2/thread
            int idx = p * 256 + tid;
            int kk = idx >> 4, n4 = (idx & 15) * 4;
            *(float4*)&Bs[kk][n4] = *(const float4*)(Wk + (size_t)(k0 + kk) * A_ + n0 + n4);
        }
        __syncthreads();
        #pragma unroll
        for (int kk = 0; kk < 32; ++kk) {
            float2 a = *(const float2*)&As[kk][ty * 2];
            float4 b = *(const float4*)&Bs[kk][tx * 4];
            acc[0][0] += a.x * b.x; acc[0][1] += a.x * b.y; acc[0][2] += a.x * b.z; acc[0][3] += a.x * b.w;
            acc[1][0] += a.y * b.x; acc[1][1] += a.y * b.y; acc[1][2] += a.y * b.z; acc[1][3] += a.y * b.w;
        }
        __syncthreads();
    }
    #pragma unroll
    for (int im = 0; im < 2; ++im) {
        float4 v = {acc[im][0], acc[im][1], acc[im][2], acc[im][3]};
        *(float4*)(ep + (size_t)(m0 + ty * 2 + im) * A_ + n0 + tx * 4) = v;
    }
}

// ---------------------------------------------------------------------------
// Decoder step: xin = [x_t, ctx_prev]@Wd+bd; h0 = cell0(xin) (i,g,o only, recomputed
// per block chunk-wise); z1 = h0@W1 (+b1) gates i,g,o -> h1, c1.
// grid: (Ngate/32=16, M/32=8), 256 threads. TM=2, TN=2, 3 gates.
__global__ __launch_bounds__(256) void k_dec_cell01(
    const float* __restrict__ x_in, const float* __restrict__ ctx_prev,
    const float* __restrict__ Wd, const float* __restrict__ bd,
    const float* __restrict__ W0, const float* __restrict__ b0,
    const float* __restrict__ W1, const float* __restrict__ b1,
    float* __restrict__ h1_out, float* __restrict__ c1_out, int t) {
    __shared__ float xinS[32];
    __shared__ float h0t[32][34];      // [k][m]
    __shared__ float Bs[3][32][32];    // [gate][k][n]
    const int tid = threadIdx.x;
    const int n0 = blockIdx.x * 32;
    const int m0 = blockIdx.y * 32;
    // ---- xin for rows m0..m0+31 (8 lanes per row within a wave)
    {
        const int wave = tid >> 6, lane = tid & 63;
        const int r = wave * 8 + (lane >> 3);
        const int sub = lane & 7;
        const int row = m0 + r;
        float s = 0.f;
        for (int k = sub * 68; k < sub * 68 + 68; ++k) {
            float xv;
            if (k < F_) xv = x_in[(size_t)row * (T_ * F_) + t * F_ + k];
            else        xv = (t == 0) ? 0.f : ctx_prev[(size_t)row * U_ + (k - F_)];
            s += xv * Wd[k];
        }
        s += __shfl_down(s, 4, 8);
        s += __shfl_down(s, 2, 8);
        s += __shfl_down(s, 1, 8);
        if (sub == 0) xinS[r] = s + bd[0];
    }
    __syncthreads();
    const int tx = tid & 15, ty = tid >> 4;
    float acc[3][2][2] = {};
    for (int k0 = 0; k0 < D_; k0 += 32) {
        // h0 chunk (gates i,g,o of cell0; c_prev=0 so f-gate dead)
        #pragma unroll
        for (int p = 0; p < 4; ++p) {
            int idx = p * 256 + tid;
            int kk = idx & 31, m = idx >> 5;
            int ka = k0 + kk;
            float xin = xinS[m];
            float zi = xin * W0[ka] + b0[ka];
            float zg = xin * W0[1024 + ka] + b0[1024 + ka];
            float zo = xin * W0[1536 + ka] + b0[1536 + ka];
            float c0 = sigf(zi) * tanh_fast(zg);
            h0t[kk][m] = sigf(zo) * tanh_fast(c0);
        }
        // W1 tiles for gates i,g,o: 3*32*32 = 768 float4-groups/4 -> 3 f4/thread
        #pragma unroll
        for (int p = 0; p < 3; ++p) {
            int f4i = p * 256 + tid;
            int g = f4i >> 8;
            int rem = f4i & 255;
            int kk = rem >> 3, n4 = (rem & 7) * 4;
            int gbase = (g == 0) ? 0 : (g == 1) ? 1024 : 1536;
            *(float4*)&Bs[g][kk][n4] =
                *(const float4*)(W1 + (size_t)(k0 + kk) * G_ + gbase + n0 + n4);
        }
        __syncthreads();
        #pragma unroll
        for (int kk = 0; kk < 32; ++kk) {
            float2 a = *(const float2*)&h0t[kk][ty * 2];
            #pragma unroll
            for (int g = 0; g < 3; ++g) {
                float2 bv = *(const float2*)&Bs[g][kk][tx * 2];
                acc[g][0][0] += a.x * bv.x; acc[g][0][1] += a.x * bv.y;
                acc[g][1][0] += a.y * bv.x; acc[g][1][1] += a.y * bv.y;
            }
        }
        __syncthreads();
    }
    #pragma unroll
    for (int im = 0; im < 2; ++im) {
        int row = m0 + ty * 2 + im;
        int col = n0 + tx * 2;
        float2 h1v, c1v;
        #pragma unroll
        for (int in = 0; in < 2; ++in) {
            float zi = acc[0][im][in] + b1[col + in];
            float zg = acc[1][im][in] + b1[1024 + col + in];
            float zo = acc[2][im][in] + b1[1536 + col + in];
            float c1 = sigf(zi) * tanh_fast(zg);
            float h1 = sigf(zo) * tanh_fast(c1);
            if (in == 0) { c1v.x = c1; h1v.x = h1; } else { c1v.y = c1; h1v.y = h1; }
        }
        *(float2*)(h1_out + (size_t)row * D_ + col) = h1v;
        *(float2*)(c1_out + (size_t)row * D_ + col) = c1v;
    }
}

// ---------------------------------------------------------------------------
// q = [h1, c1] @ Wq  (M=256, K=1024, N=512). BM=32,BN=32, TM=2,TN=2. grid (16,8)
__global__ __launch_bounds__(256) void k_dec_q(
    const float* __restrict__ h1, const float* __restrict__ c1,
    const float* __restrict__ Wq, float* __restrict__ q) {
    __shared__ float As[32][34];
    __shared__ float Bs[32][32];
    const int n0 = blockIdx.x * 32, m0 = blockIdx.y * 32;
    const int tid = threadIdx.x, tx = tid & 15, ty = tid >> 4;
    float acc[2][2] = {};
    for (int k0 = 0; k0 < 2 * D_; k0 += 32) {
        const float* src = (k0 < D_) ? h1 : c1;
        const int kb = k0 & (D_ - 1);
        {
            int m = tid >> 3, k4 = (tid & 7) * 4;
            float4 v = *(const float4*)(src + (size_t)(m0 + m) * D_ + kb + k4);
            As[k4 + 0][m] = v.x; As[k4 + 1][m] = v.y; As[k4 + 2][m] = v.z; As[k4 + 3][m] = v.w;
        }
        {
            int kk = tid >> 3, n4 = (tid & 7) * 4;
            *(float4*)&Bs[kk][n4] = *(const float4*)(Wq + (size_t)(k0 + kk) * A_ + n0 + n4);
        }
        __syncthreads();
        #pragma unroll
        for (int kk = 0; kk < 32; ++kk) {
            float2 a = *(const float2*)&As[kk][ty * 2];
            float2 b = *(const float2*)&Bs[kk][tx * 2];
            acc[0][0] += a.x * b.x; acc[0][1] += a.x * b.y;
            acc[1][0] += a.y * b.x; acc[1][1] += a.y * b.y;
        }
        __syncthreads();
    }
    #pragma unroll
    for (int im = 0; im < 2; ++im) {
        float2 v = {acc[im][0], acc[im][1]};
        *(float2*)(q + (size_t)(m0 + ty * 2 + im) * A_ + n0 + tx * 2) = v;
    }
}

// ---------------------------------------------------------------------------
// Attention: score[t'] = sum_a tanh(q[b,a]+ep[b,t',a])*v[a]; softmax over t';
// ctx[b,u] = sum_t' w[t'] * enc[b,t',u].  One block per b, 256 threads.
__global__ __launch_bounds__(256) void k_attn(
    const float* __restrict__ q, const float* __restrict__ ep,
    const float* __restrict__ enc, const float* __restrict__ v_att,
    float* __restrict__ ctx_out) {
    const int b = blockIdx.x;
    const int tid = threadIdx.x;
    __shared__ float qs[512], vs[512];
    __shared__ float sc[128];
    __shared__ float red[8];
    #pragma unroll
    for (int p = 0; p < 2; ++p) {
        qs[p * 256 + tid] = q[(size_t)b * A_ + p * 256 + tid];
        vs[p * 256 + tid] = v_att[p * 256 + tid];
    }
    __syncthreads();
    const int wave = tid >> 6, lane = tid & 63;
    for (int tp = wave; tp < T_; tp += 4) {
        const float* row = ep + ((size_t)b * T_ + tp) * A_;
        float s = 0.f;
        #pragma unroll
        for (int i = 0; i < 8; ++i) {
            int a = lane + 64 * i;
            s += tanh_fast(qs[a] + row[a]) * vs[a];
        }
        #pragma unroll
        for (int off = 32; off; off >>= 1) s += __shfl_xor(s, off);
        if (lane == 0) sc[tp] = s;
    }
    __syncthreads();
    float vscore = 0.f;
    if (tid < 128) {
        vscore = sc[tid];
        float m = vscore;
        #pragma unroll
        for (int off = 32; off; off >>= 1) m = fmaxf(m, __shfl_xor(m, off));
        if (lane == 0) red[wave] = m;
    }
    __syncthreads();
    if (tid < 128) {
        float gm = fmaxf(red[0], red[1]);
        float e = __expf(vscore - gm);
        sc[tid] = e;
        float ss = e;
        #pragma unroll
        for (int off = 32; off; off >>= 1) ss += __shfl_xor(ss, off);
        if (lane == 0) red[4 + wave] = ss;
    }
    __syncthreads();
    const float inv = 1.0f / (red[4] + red[5]);
    #pragma unroll
    for (int p = 0; p < 2; ++p) {
        int u = p * 256 + tid;
        float acc = 0.f;
        const float* ecol = enc + (size_t)b * (T_ * U_) + u;
        #pragma unroll 4
        for (int tp = 0; tp < T_; ++tp) acc += sc[tp] * ecol[(size_t)tp * U_];
        ctx_out[(size_t)b * U_ + u] = acc * inv;
    }
}

// ---------------------------------------------------------------------------
// Final LSTM partial GEMMs: zp[s] = A_s @ B_s over K=512 each.
// s=0: gathered h1 rows @ Wf[0:512];  s=1: gathered ctx @ Wf[512:1024];  s=2: h_f @ Uf.
// Row gather: i -> t'=i>>1, b'=j+128*(i&1).  BM=32,BN=64,TM=2,TN=4. grid (32,8,3)
__global__ __launch_bounds__(256) void k_f_gemm(
    const float* __restrict__ h1_all, const float* __restrict__ ctx_all,
    const float* __restrict__ h_f,
    const float* __restrict__ Wf, const float* __restrict__ Uf,
    float* __restrict__ zp, int j) {
    __shared__ float As[32][34];
    __shared__ float Bs[32][64];
    const int s = blockIdx.z;
    const int n0 = blockIdx.x * 64, m0 = blockIdx.y * 32;
    const int tid = threadIdx.x, tx = tid & 15, ty = tid >> 4;
    const float* Bsrc = (s == 0) ? Wf : (s == 1) ? (Wf + (size_t)512 * G_) : Uf;
    float acc[2][4] = {};
    for (int k0 = 0; k0 < 512; k0 += 32) {
        {
            int m = tid >> 3, k4 = (tid & 7) * 4;
            int i = m0 + m;
            const float* arow;
            if (s == 2) arow = h_f + (size_t)i * D_;
            else {
                int tp = i >> 1, bp = j + 128 * (i & 1);
                arow = ((s == 0) ? h1_all : ctx_all) + ((size_t)tp * B_ + bp) * D_;
            }
            float4 v = *(const float4*)(arow + k0 + k4);
            As[k4 + 0][m] = v.x; As[k4 + 1][m] = v.y; As[k4 + 2][m] = v.z; As[k4 + 3][m] = v.w;
        }
        #pragma unroll
        for (int p = 0; p < 2; ++p) {
            int idx = p * 256 + tid;
            int kk = idx >> 4, n4 = (idx & 15) * 4;
            *(float4*)&Bs[kk][n4] = *(const float4*)(Bsrc + (size_t)(k0 + kk) * G_ + n0 + n4);
        }
        __syncthreads();
        #pragma unroll
        for (int kk = 0; kk < 32; ++kk) {
            float2 a = *(const float2*)&As[kk][ty * 2];
            float4 b = *(const float4*)&Bs[kk][tx * 4];
            acc[0][0] += a.x * b.x; acc[0][1] += a.x * b.y; acc[0][2] += a.x * b.z; acc[0][3] += a.x * b.w;
            acc[1][0] += a.y * b.x; acc[1][1] += a.y * b.y; acc[1][2] += a.y * b.z; acc[1][3] += a.y * b.w;
        }
        __syncthreads();
    }
    float* dst = zp + (size_t)s * (B_ * G_);
    #pragma unroll
    for (int im = 0; im < 2; ++im) {
        float4 v = {acc[im][0], acc[im][1], acc[im][2], acc[im][3]};
        *(float4*)(dst + (size_t)(m0 + ty * 2 + im) * G_ + n0 + tx * 4) = v;
    }
}

// ---------------------------------------------------------------------------
// Final LSTM gates: z = zp0+zp1+zp2+bf; full i,f,g,o; update h_f,c_f; write out.
__global__ __launch_bounds__(256) void k_f_gate(
    const float* __restrict__ zp, const float* __restrict__ bf,
    float* __restrict__ h_f, float* __restrict__ c_f,
    float* __restrict__ out, int j) {
    const int i = blockIdx.x;
    const int tid = threadIdx.x;
    #pragma unroll
    for (int p = 0; p < 2; ++p) {
        int d = p * 256 + tid;
        float zi = bf[d], zf = bf[512 + d], zg = bf[1024 + d], zo = bf[1536 + d];
        #pragma unroll
        for (int s = 0; s < 3; ++s) {
            const float* z = zp + (size_t)s * (B_ * G_) + (size_t)i * G_;
            zi += z[d]; zf += z[512 + d]; zg += z[1024 + d]; zo += z[1536 + d];
        }
        float c_old = c_f[(size_t)i * D_ + d];
        float cn = sigf(zf) * c_old + sigf(zi) * tanh_fast(zg);
        float hn = sigf(zo) * tanh_fast(cn);
        c_f[(size_t)i * D_ + d] = cn;
        h_f[(size_t)i * D_ + d] = hn;
        out[((size_t)i * T_ + j) * D_ + d] = hn;
    }
}

// ---------------------------------------------------------------------------
extern "C" void kernel_launch(void* const* d_in, const int* in_sizes, int n_in,
                              void* d_out, int out_size, void* d_ws, size_t ws_size,
                              hipStream_t stream) {
    const float* inputs = (const float*)d_in[0];
    const float* enc    = (const float*)d_in[1];
    const float* Wd     = (const float*)d_in[2];
    const float* bd     = (const float*)d_in[3];
    const float* W0     = (const float*)d_in[4];
    // d_in[5] = U0 unused (h=0 in per-step LSTM cell 0)
    const float* b0     = (const float*)d_in[6];
    const float* W1     = (const float*)d_in[7];
    // d_in[8] = U1 unused
    const float* b1     = (const float*)d_in[9];
    const float* Wq     = (const float*)d_in[10];
    const float* Wk     = (const float*)d_in[11];
    const float* v_att  = (const float*)d_in[12];
    const float* Wf     = (const float*)d_in[13];
    const float* Uf     = (const float*)d_in[14];
    const float* bf     = (const float*)d_in[15];
    float* out = (float*)d_out;

    float* ws = (float*)d_ws;
    float* ep      = ws;                                  // [B][T][A]   16.7M f
    float* h1_all  = ep      + (size_t)B_ * T_ * A_;      // [T][B][D]   16.7M f
    float* ctx_all = h1_all  + (size_t)T_ * B_ * D_;      // [T][B][U]   16.7M f
    float* c1      = ctx_all + (size_t)T_ * B_ * U_;      // [B][D]
    float* qbuf    = c1      + (size_t)B_ * D_;           // [B][A]
    float* zp      = qbuf    + (size_t)B_ * A_;           // [3][B][G]
    float* h_f     = zp      + (size_t)3 * B_ * G_;       // [B][D]
    float* c_f     = h_f     + (size_t)B_ * D_;           // [B][D]

    hipMemsetAsync(h_f, 0, (size_t)B_ * D_ * sizeof(float), stream);
    hipMemsetAsync(c_f, 0, (size_t)B_ * D_ * sizeof(float), stream);

    k_encproj<<<dim3(A_ / 64, (B_ * T_) / 32), 256, 0, stream>>>(enc, Wk, ep);

    for (int t = 0; t < T_; ++t) {
        const float* ctx_prev = ctx_all + (size_t)((t == 0) ? 0 : (t - 1)) * B_ * U_;
        float* h1_t  = h1_all  + (size_t)t * B_ * D_;
        float* ctx_t = ctx_all + (size_t)t * B_ * U_;
        k_dec_cell01<<<dim3(16, 8), 256, 0, stream>>>(inputs, ctx_prev, Wd, bd, W0, b0,
                                                      W1, b1, h1_t, c1, t);
        k_dec_q<<<dim3(16, 8), 256, 0, stream>>>(h1_t, c1, Wq, qbuf);
        k_attn<<<dim3(B_), 256, 0, stream>>>(qbuf, ep, enc, v_att, ctx_t);
    }
    for (int j = 0; j < T_; ++j) {
        k_f_gemm<<<dim3(G_ / 64, B_ / 32, 3), 256, 0, stream>>>(h1_all, ctx_all, h_f,
                                                                Wf, Uf, zp, j);
        k_f_gate<<<dim3(B_), 256, 0, stream>>>(zp, bf, h_f, c_f, out, j);
    }
}

// Round 2
// 10153.551 us; speedup vs baseline: 2.0486x; 2.0486x over previous
//
#include <hip/hip_runtime.h>

// Problem constants
constexpr int B_ = 256;
constexpr int T_ = 128;
constexpr int F_ = 32;
constexpr int U_ = 512;   // U_ENC
constexpr int D_ = 512;
constexpr int A_ = 512;
constexpr int G_ = 2048;  // 4*D

// xin lookup table
constexpr int   NS_   = 4096;
constexpr float LO_   = -16.0f;
constexpr float IDT_  = 128.0f;   // NS / 32

__device__ __forceinline__ float sigf(float x) { return 1.0f / (1.0f + __expf(-x)); }
__device__ __forceinline__ float tanh_fast(float x) {
    return 2.0f / (1.0f + __expf(-2.0f * x)) - 1.0f;
}

// ---------------------------------------------------------------------------
// Generic f32 GEMM: C[M,N] = A[M,K]@B[K,N].  BM=BN=128, BK=16, TM=TN=8.
// 256 threads as 16x16 (tx=n, ty=m). A staged transposed for b128 col reads.
// Grid: (N/128, M/128). All dims assumed divisible.
__global__ __launch_bounds__(256) void k_gemm128(
    const float* __restrict__ A, int lda,
    const float* __restrict__ Bm, int ldb,
    float* __restrict__ C, int ldc, int K) {
    constexpr int BK = 16;
    __shared__ float As[BK][132];
    __shared__ float Bs[BK][128];
    const int tid = threadIdx.x;
    const int tx = tid & 15, ty = tid >> 4;
    const int m0 = blockIdx.y * 128, n0 = blockIdx.x * 128;
    // staging coords (2 float4 per thread for each of A and B)
    const int am0 = tid >> 2,          ak40 = (tid & 3) * 4;        // idx = tid
    const int am1 = (256 + tid) >> 2,  ak41 = ((256 + tid) & 3) * 4;
    const int bk0 = tid >> 5,          bn40 = (tid & 31) * 4;
    const int bk1 = (256 + tid) >> 5,  bn41 = ((256 + tid) & 31) * 4;
    const float* a0p = A + (size_t)(m0 + am0) * lda + ak40;
    const float* a1p = A + (size_t)(m0 + am1) * lda + ak41;
    const float* b0p = Bm + (size_t)bk0 * ldb + n0 + bn40;
    const float* b1p = Bm + (size_t)bk1 * ldb + n0 + bn41;
    float4 ar0 = *(const float4*)(a0p);
    float4 ar1 = *(const float4*)(a1p);
    float4 br0 = *(const float4*)(b0p);
    float4 br1 = *(const float4*)(b1p);
    float acc[8][8] = {};
    for (int k0 = 0; k0 < K; k0 += BK) {
        __syncthreads();
        As[ak40 + 0][am0] = ar0.x; As[ak40 + 1][am0] = ar0.y;
        As[ak40 + 2][am0] = ar0.z; As[ak40 + 3][am0] = ar0.w;
        As[ak41 + 0][am1] = ar1.x; As[ak41 + 1][am1] = ar1.y;
        As[ak41 + 2][am1] = ar1.z; As[ak41 + 3][am1] = ar1.w;
        *(float4*)&Bs[bk0][bn40] = br0;
        *(float4*)&Bs[bk1][bn41] = br1;
        __syncthreads();
        if (k0 + BK < K) {
            ar0 = *(const float4*)(a0p + k0 + BK);
            ar1 = *(const float4*)(a1p + k0 + BK);
            br0 = *(const float4*)(b0p + (size_t)(k0 + BK) * ldb);
            br1 = *(const float4*)(b1p + (size_t)(k0 + BK) * ldb);
        }
        #pragma unroll
        for (int kk = 0; kk < BK; ++kk) {
            float a[8], b[8];
            *(float4*)&a[0] = *(const float4*)&As[kk][ty * 8];
            *(float4*)&a[4] = *(const float4*)&As[kk][ty * 8 + 4];
            *(float4*)&b[0] = *(const float4*)&Bs[kk][tx * 8];
            *(float4*)&b[4] = *(const float4*)&Bs[kk][tx * 8 + 4];
            #pragma unroll
            for (int im = 0; im < 8; ++im)
                #pragma unroll
                for (int in = 0; in < 8; ++in)
                    acc[im][in] += a[im] * b[in];
        }
    }
    #pragma unroll
    for (int im = 0; im < 8; ++im) {
        float* crow = C + (size_t)(m0 + ty * 8 + im) * ldc + n0 + tx * 8;
        *(float4*)(crow)     = make_float4(acc[im][0], acc[im][1], acc[im][2], acc[im][3]);
        *(float4*)(crow + 4) = make_float4(acc[im][4], acc[im][5], acc[im][6], acc[im][7]);
    }
}

// ---------------------------------------------------------------------------
// h0 table: h0T[s][k] = cell0 hidden for scalar input s_val (c_prev=h_prev=0)
__global__ __launch_bounds__(256) void k_h0build(
    const float* __restrict__ W0, const float* __restrict__ b0,
    float* __restrict__ h0T) {
    int idx4 = blockIdx.x * 256 + threadIdx.x;      // 4 elems each
    int s = idx4 >> 7, kq = (idx4 & 127) * 4;
    float sv = LO_ + (float)s * (1.0f / IDT_);
    float4 o;
    float* po = &o.x;
    #pragma unroll
    for (int jj = 0; jj < 4; ++jj) {
        int k = kq + jj;
        float zi = sv * W0[k] + b0[k];
        float zg = sv * W0[1024 + k] + b0[1024 + k];
        float zo = sv * W0[1536 + k] + b0[1536 + k];
        float c0 = sigf(zi) * tanh_fast(zg);
        po[jj] = sigf(zo) * tanh_fast(c0);
    }
    *(float4*)(h0T + (size_t)s * D_ + kq) = o;
}

// z1T -> h1c1T (h1 in cols [0,512), c1 in [512,1024))
__global__ __launch_bounds__(256) void k_gates1(
    const float* __restrict__ z1T, const float* __restrict__ b1,
    float* __restrict__ h1c1T) {
    int idx4 = blockIdx.x * 256 + threadIdx.x;
    int s = idx4 >> 7, dq = (idx4 & 127) * 4;
    const float* z = z1T + (size_t)s * G_;
    float4 hv, cv;
    float* ph = &hv.x; float* pc = &cv.x;
    #pragma unroll
    for (int jj = 0; jj < 4; ++jj) {
        int d = dq + jj;
        float zi = z[d] + b1[d];
        float zg = z[1024 + d] + b1[1024 + d];
        float zo = z[1536 + d] + b1[1536 + d];
        float c1 = sigf(zi) * tanh_fast(zg);
        pc[jj] = c1;
        ph[jj] = sigf(zo) * tanh_fast(c1);
    }
    *(float4*)(h1c1T + (size_t)s * (2 * D_) + dq) = hv;
    *(float4*)(h1c1T + (size_t)s * (2 * D_) + D_ + dq) = cv;
}

// xd[b*T+t] = inputs[b,t,:]@Wd[0:32] + bd
__global__ __launch_bounds__(256) void k_xd(
    const float* __restrict__ inp, const float* __restrict__ Wd,
    const float* __restrict__ bd, float* __restrict__ xd) {
    int id = blockIdx.x * 256 + threadIdx.x;  // b*T + t
    const float* row = inp + (size_t)id * F_;
    float s = 0.f;
    #pragma unroll
    for (int f = 0; f < F_; ++f) s += row[f] * Wd[f];
    xd[id] = s + bd[0];
}

// ---------------------------------------------------------------------------
// Fused decoder step: xin = xd + ctx_prev@Wd2; q = interp(qT); attention;
// write ctx_all[t], xin_all[t]. One block per batch b.
__global__ __launch_bounds__(256) void k_step(
    const float* __restrict__ xd, const float* __restrict__ Wd2,
    const float* __restrict__ qT, const float* __restrict__ v_att,
    const float* __restrict__ ep, const float* __restrict__ enc,
    const float* __restrict__ ctx_prev,
    float* __restrict__ ctx_out, float* __restrict__ xin_all, int t) {
    const int b = blockIdx.x;
    const int tid = threadIdx.x;
    const int wave = tid >> 6, lane = tid & 63;
    __shared__ float qs[512], vs[512], sc[128], red[16];
    // ---- xin
    float part = 0.f;
    if (t > 0) {
        const float* cp = ctx_prev + (size_t)b * U_;
        part = cp[tid] * Wd2[tid] + cp[tid + 256] * Wd2[tid + 256];
    }
    #pragma unroll
    for (int off = 32; off; off >>= 1) part += __shfl_xor(part, off);
    if (lane == 0) red[8 + wave] = part;
    __syncthreads();
    const float xin = xd[b * T_ + t] + red[8] + red[9] + red[10] + red[11];
    if (tid == 0) xin_all[t * B_ + b] = xin;
    // ---- q interp + v stage
    float u = (xin - LO_) * IDT_;
    u = fminf(fmaxf(u, 0.0f), (float)NS_ - 1.001f);
    int i0 = (int)u; float fr = u - (float)i0;
    #pragma unroll
    for (int p = 0; p < 2; ++p) {
        int a = p * 256 + tid;
        float lo = qT[(size_t)i0 * A_ + a];
        float hi = qT[(size_t)(i0 + 1) * A_ + a];
        qs[a] = lo + fr * (hi - lo);
        vs[a] = v_att[a];
    }
    __syncthreads();
    // ---- scores
    for (int tp = wave; tp < T_; tp += 4) {
        const float* row = ep + ((size_t)b * T_ + tp) * A_;
        float s = 0.f;
        #pragma unroll
        for (int i = 0; i < 8; ++i) {
            int a = lane + 64 * i;
            s += tanh_fast(qs[a] + row[a]) * vs[a];
        }
        #pragma unroll
        for (int off = 32; off; off >>= 1) s += __shfl_xor(s, off);
        if (lane == 0) sc[tp] = s;
    }
    __syncthreads();
    // ---- softmax
    float vscore = 0.f;
    if (tid < 128) {
        vscore = sc[tid];
        float m = vscore;
        #pragma unroll
        for (int off = 32; off; off >>= 1) m = fmaxf(m, __shfl_xor(m, off));
        if (lane == 0) red[wave] = m;
    }
    __syncthreads();
    if (tid < 128) {
        float gm = fmaxf(red[0], red[1]);
        float e = __expf(vscore - gm);
        sc[tid] = e;
        float ss = e;
        #pragma unroll
        for (int off = 32; off; off >>= 1) ss += __shfl_xor(ss, off);
        if (lane == 0) red[4 + wave] = ss;
    }
    __syncthreads();
    const float inv = 1.0f / (red[4] + red[5]);
    // ---- context
    #pragma unroll
    for (int p = 0; p < 2; ++p) {
        int u2 = p * 256 + tid;
        float acc = 0.f;
        const float* ecol = enc + (size_t)b * (T_ * U_) + u2;
        #pragma unroll 4
        for (int tp = 0; tp < T_; ++tp) acc += sc[tp] * ecol[(size_t)tp * U_];
        ctx_out[(size_t)b * U_ + u2] = acc * inv;
    }
}

// ---------------------------------------------------------------------------
// Final LSTM split-K GEMM: zp[s][i][n], s=0: h_f@Uf; s=1: gathered-ctx@Wf2.
// BM=64,BN=64,BK=16,TM=TN=4. grid (2048/64, 256/64, 2) = (32,4,2).
__global__ __launch_bounds__(256) void k_fstep(
    const float* __restrict__ h_f, const float* __restrict__ ctx_all,
    const float* __restrict__ Uf, const float* __restrict__ Wf2,
    float* __restrict__ zp, int j) {
    constexpr int BK = 16;
    __shared__ float As[BK][68];
    __shared__ float Bs[BK][64];
    const int s = blockIdx.z;
    const int n0 = blockIdx.x * 64, m0 = blockIdx.y * 64;
    const int tid = threadIdx.x, tx = tid & 15, ty = tid >> 4;
    const int am = tid >> 2, ak4 = (tid & 3) * 4;
    const float* arow;
    {
        int i = m0 + am;
        if (s == 0) arow = h_f + (size_t)i * D_;
        else {
            int tt = i >> 1, bb = ((i & 1) << 7) + j;
            arow = ctx_all + ((size_t)tt * B_ + bb) * U_;
        }
    }
    const float* Bmat = (s == 0) ? Uf : Wf2;
    const int bk = tid >> 4, bn4 = (tid & 15) * 4;
    const float* bp = Bmat + (size_t)bk * G_ + n0 + bn4;
    float4 ar = *(const float4*)(arow + ak4);
    float4 br = *(const float4*)(bp);
    float acc[4][4] = {};
    for (int k0 = 0; k0 < 512; k0 += BK) {
        __syncthreads();
        As[ak4 + 0][am] = ar.x; As[ak4 + 1][am] = ar.y;
        As[ak4 + 2][am] = ar.z; As[ak4 + 3][am] = ar.w;
        *(float4*)&Bs[bk][bn4] = br;
        __syncthreads();
        if (k0 + BK < 512) {
            ar = *(const float4*)(arow + k0 + BK + ak4);
            br = *(const float4*)(bp + (size_t)(k0 + BK) * G_);
        }
        #pragma unroll
        for (int kk = 0; kk < BK; ++kk) {
            float4 a = *(const float4*)&As[kk][ty * 4];
            float4 b = *(const float4*)&Bs[kk][tx * 4];
            acc[0][0] += a.x * b.x; acc[0][1] += a.x * b.y; acc[0][2] += a.x * b.z; acc[0][3] += a.x * b.w;
            acc[1][0] += a.y * b.x; acc[1][1] += a.y * b.y; acc[1][2] += a.y * b.z; acc[1][3] += a.y * b.w;
            acc[2][0] += a.z * b.x; acc[2][1] += a.z * b.y; acc[2][2] += a.z * b.z; acc[2][3] += a.z * b.w;
            acc[3][0] += a.w * b.x; acc[3][1] += a.w * b.y; acc[3][2] += a.w * b.z; acc[3][3] += a.w * b.w;
        }
    }
    float* dst = zp + (size_t)s * (B_ * G_);
    #pragma unroll
    for (int im = 0; im < 4; ++im)
        *(float4*)(dst + (size_t)(m0 + ty * 4 + im) * G_ + n0 + tx * 4) =
            make_float4(acc[im][0], acc[im][1], acc[im][2], acc[im][3]);
}

// Final gates: z = zp0+zp1 + interp(zhT) + bf; update h_f,c_f; write out[i][j].
__global__ __launch_bounds__(256) void k_fgate(
    const float* __restrict__ zp, const float* __restrict__ zhT,
    const float* __restrict__ xinA, const float* __restrict__ bf,
    float* __restrict__ h_f, float* __restrict__ c_f,
    float* __restrict__ out, int j) {
    const int i = blockIdx.x, tid = threadIdx.x;
    const int tt = i >> 1, bb = ((i & 1) << 7) + j;
    float xin = xinA[tt * B_ + bb];
    float u = (xin - LO_) * IDT_;
    u = fminf(fmaxf(u, 0.0f), (float)NS_ - 1.001f);
    int i0 = (int)u; float fr = u - (float)i0;
    const float* zh0 = zhT + (size_t)i0 * G_;
    const float* zh1 = zh0 + G_;
    const float* z0 = zp + (size_t)i * G_;
    const float* z1 = zp + (size_t)(B_ + i) * G_;
    #pragma unroll
    for (int p = 0; p < 2; ++p) {
        int d = p * 256 + tid;
        float zg4[4];
        #pragma unroll
        for (int g = 0; g < 4; ++g) {
            int col = g * 512 + d;
            float lo = zh0[col];
            zg4[g] = z0[col] + z1[col] + lo + fr * (zh1[col] - lo) + bf[col];
        }
        float c_old = c_f[(size_t)i * D_ + d];
        float cn = sigf(zg4[1]) * c_old + sigf(zg4[0]) * tanh_fast(zg4[2]);
        float hn = sigf(zg4[3]) * tanh_fast(cn);
        c_f[(size_t)i * D_ + d] = cn;
        h_f[(size_t)i * D_ + d] = hn;
        out[((size_t)i * T_ + j) * D_ + d] = hn;
    }
}

// ---------------------------------------------------------------------------
extern "C" void kernel_launch(void* const* d_in, const int* in_sizes, int n_in,
                              void* d_out, int out_size, void* d_ws, size_t ws_size,
                              hipStream_t stream) {
    const float* inputs = (const float*)d_in[0];
    const float* enc    = (const float*)d_in[1];
    const float* Wd     = (const float*)d_in[2];
    const float* bd     = (const float*)d_in[3];
    const float* W0     = (const float*)d_in[4];
    // d_in[5] = U0 unused (zero initial state per step)
    const float* b0     = (const float*)d_in[6];
    const float* W1     = (const float*)d_in[7];
    // d_in[8] = U1 unused
    const float* b1     = (const float*)d_in[9];
    const float* Wq     = (const float*)d_in[10];
    const float* Wk     = (const float*)d_in[11];
    const float* v_att  = (const float*)d_in[12];
    const float* Wf     = (const float*)d_in[13];
    const float* Uf     = (const float*)d_in[14];
    const float* bf     = (const float*)d_in[15];
    float* out = (float*)d_out;

    float* ws = (float*)d_ws;
    float* ep      = ws;                          // 16,777,216  [B][T][A]
    float* ctx_all = ep + (size_t)16777216;       // 16,777,216  [T][B][U]
    float* qT      = ctx_all + (size_t)16777216;  //  2,097,152  [NS][A]
    float* zhT     = qT + (size_t)2097152;        //  8,388,608  [NS][G]
    float* h0T     = zhT + (size_t)8388608;       //  2,097,152  [NS][D]
    float* h1c1T   = h0T + (size_t)2097152;       //  4,194,304  [NS][2D]
    float* xd      = h1c1T + (size_t)4194304;     //     32,768  [B][T]
    float* xinA    = xd + 32768;                  //     32,768  [T][B]
    float* zp      = xinA + 32768;                //  1,048,576  [2][B][G]
    float* h_f     = zp + 1048576;                //    131,072
    float* c_f     = h_f + 131072;                //    131,072
    float* z1T     = ep;                          // alias (consumed pre-encproj)

    // ---- tables (one-time per launch)
    k_h0build<<<dim3(NS_ * D_ / 1024), 256, 0, stream>>>(W0, b0, h0T);
    k_gemm128<<<dim3(G_ / 128, NS_ / 128), 256, 0, stream>>>(h0T, D_, W1, G_, z1T, G_, D_);
    k_gates1<<<dim3(NS_ * D_ / 1024), 256, 0, stream>>>(z1T, b1, h1c1T);
    k_gemm128<<<dim3(A_ / 128, NS_ / 128), 256, 0, stream>>>(h1c1T, 2 * D_, Wq, A_, qT, A_, 2 * D_);
    k_gemm128<<<dim3(G_ / 128, NS_ / 128), 256, 0, stream>>>(h1c1T, 2 * D_, Wf, G_, zhT, G_, D_);
    k_xd<<<dim3(B_ * T_ / 256), 256, 0, stream>>>(inputs, Wd, bd, xd);
    // enc projection (overwrites z1T alias region — already consumed)
    k_gemm128<<<dim3(A_ / 128, (B_ * T_) / 128), 256, 0, stream>>>(enc, U_, Wk, A_, ep, A_, U_);

    hipMemsetAsync(h_f, 0, (size_t)B_ * D_ * sizeof(float), stream);
    hipMemsetAsync(c_f, 0, (size_t)B_ * D_ * sizeof(float), stream);

    // ---- decoder loop
    for (int t = 0; t < T_; ++t) {
        const float* ctx_prev = ctx_all + (size_t)((t == 0) ? 0 : (t - 1)) * B_ * U_;
        float* ctx_t = ctx_all + (size_t)t * B_ * U_;
        k_step<<<dim3(B_), 256, 0, stream>>>(xd, Wd + F_, qT, v_att, ep, enc,
                                             ctx_prev, ctx_t, xinA, t);
    }
    // ---- final LSTM loop
    const float* Wf2 = Wf + (size_t)D_ * G_;
    for (int j = 0; j < T_; ++j) {
        k_fstep<<<dim3(G_ / 64, B_ / 64, 2), 256, 0, stream>>>(h_f, ctx_all, Uf, Wf2, zp, j);
        k_fgate<<<dim3(B_), 256, 0, stream>>>(zp, zhT, xinA, bf, h_f, c_f, out, j);
    }
}

// Round 3
// 7574.833 us; speedup vs baseline: 2.7461x; 1.3404x over previous
//
#include <hip/hip_runtime.h>

// Problem constants
constexpr int B_ = 256;
constexpr int T_ = 128;
constexpr int F_ = 32;
constexpr int U_ = 512;   // U_ENC
constexpr int D_ = 512;
constexpr int A_ = 512;
constexpr int G_ = 2048;  // 4*D

// xin lookup table
constexpr int   NS_   = 4096;
constexpr float LO_   = -16.0f;
constexpr float IDT_  = 128.0f;   // NS / 32

__device__ __forceinline__ float sigf(float x) { return 1.0f / (1.0f + __expf(-x)); }
__device__ __forceinline__ float tanh_fast(float x) {
    return 2.0f / (1.0f + __expf(-2.0f * x)) - 1.0f;
}

// ---------------------------------------------------------------------------
// Generic f32 GEMM: C[M,N] = A[M,K]@B[K,N].  BM=BN=128, BK=16, TM=TN=8.
__global__ __launch_bounds__(256) void k_gemm128(
    const float* __restrict__ A, int lda,
    const float* __restrict__ Bm, int ldb,
    float* __restrict__ C, int ldc, int K) {
    constexpr int BK = 16;
    __shared__ float As[BK][132];
    __shared__ float Bs[BK][128];
    const int tid = threadIdx.x;
    const int tx = tid & 15, ty = tid >> 4;
    const int m0 = blockIdx.y * 128, n0 = blockIdx.x * 128;
    const int am0 = tid >> 2,          ak40 = (tid & 3) * 4;
    const int am1 = (256 + tid) >> 2,  ak41 = ((256 + tid) & 3) * 4;
    const int bk0 = tid >> 5,          bn40 = (tid & 31) * 4;
    const int bk1 = (256 + tid) >> 5,  bn41 = ((256 + tid) & 31) * 4;
    const float* a0p = A + (size_t)(m0 + am0) * lda + ak40;
    const float* a1p = A + (size_t)(m0 + am1) * lda + ak41;
    const float* b0p = Bm + (size_t)bk0 * ldb + n0 + bn40;
    const float* b1p = Bm + (size_t)bk1 * ldb + n0 + bn41;
    float4 ar0 = *(const float4*)(a0p);
    float4 ar1 = *(const float4*)(a1p);
    float4 br0 = *(const float4*)(b0p);
    float4 br1 = *(const float4*)(b1p);
    float acc[8][8] = {};
    for (int k0 = 0; k0 < K; k0 += BK) {
        __syncthreads();
        As[ak40 + 0][am0] = ar0.x; As[ak40 + 1][am0] = ar0.y;
        As[ak40 + 2][am0] = ar0.z; As[ak40 + 3][am0] = ar0.w;
        As[ak41 + 0][am1] = ar1.x; As[ak41 + 1][am1] = ar1.y;
        As[ak41 + 2][am1] = ar1.z; As[ak41 + 3][am1] = ar1.w;
        *(float4*)&Bs[bk0][bn40] = br0;
        *(float4*)&Bs[bk1][bn41] = br1;
        __syncthreads();
        if (k0 + BK < K) {
            ar0 = *(const float4*)(a0p + k0 + BK);
            ar1 = *(const float4*)(a1p + k0 + BK);
            br0 = *(const float4*)(b0p + (size_t)(k0 + BK) * ldb);
            br1 = *(const float4*)(b1p + (size_t)(k0 + BK) * ldb);
        }
        #pragma unroll
        for (int kk = 0; kk < BK; ++kk) {
            float a[8], b[8];
            *(float4*)&a[0] = *(const float4*)&As[kk][ty * 8];
            *(float4*)&a[4] = *(const float4*)&As[kk][ty * 8 + 4];
            *(float4*)&b[0] = *(const float4*)&Bs[kk][tx * 8];
            *(float4*)&b[4] = *(const float4*)&Bs[kk][tx * 8 + 4];
            #pragma unroll
            for (int im = 0; im < 8; ++im)
                #pragma unroll
                for (int in = 0; in < 8; ++in)
                    acc[im][in] += a[im] * b[in];
        }
    }
    #pragma unroll
    for (int im = 0; im < 8; ++im) {
        float* crow = C + (size_t)(m0 + ty * 8 + im) * ldc + n0 + tx * 8;
        *(float4*)(crow)     = make_float4(acc[im][0], acc[im][1], acc[im][2], acc[im][3]);
        *(float4*)(crow + 4) = make_float4(acc[im][4], acc[im][5], acc[im][6], acc[im][7]);
    }
}

// ---------------------------------------------------------------------------
__global__ __launch_bounds__(256) void k_h0build(
    const float* __restrict__ W0, const float* __restrict__ b0,
    float* __restrict__ h0T) {
    int idx4 = blockIdx.x * 256 + threadIdx.x;
    int s = idx4 >> 7, kq = (idx4 & 127) * 4;
    float sv = LO_ + (float)s * (1.0f / IDT_);
    float4 o;
    float* po = &o.x;
    #pragma unroll
    for (int jj = 0; jj < 4; ++jj) {
        int k = kq + jj;
        float zi = sv * W0[k] + b0[k];
        float zg = sv * W0[1024 + k] + b0[1024 + k];
        float zo = sv * W0[1536 + k] + b0[1536 + k];
        float c0 = sigf(zi) * tanh_fast(zg);
        po[jj] = sigf(zo) * tanh_fast(c0);
    }
    *(float4*)(h0T + (size_t)s * D_ + kq) = o;
}

__global__ __launch_bounds__(256) void k_gates1(
    const float* __restrict__ z1T, const float* __restrict__ b1,
    float* __restrict__ h1c1T) {
    int idx4 = blockIdx.x * 256 + threadIdx.x;
    int s = idx4 >> 7, dq = (idx4 & 127) * 4;
    const float* z = z1T + (size_t)s * G_;
    float4 hv, cv;
    float* ph = &hv.x; float* pc = &cv.x;
    #pragma unroll
    for (int jj = 0; jj < 4; ++jj) {
        int d = dq + jj;
        float zi = z[d] + b1[d];
        float zg = z[1024 + d] + b1[1024 + d];
        float zo = z[1536 + d] + b1[1536 + d];
        float c1 = sigf(zi) * tanh_fast(zg);
        pc[jj] = c1;
        ph[jj] = sigf(zo) * tanh_fast(c1);
    }
    *(float4*)(h1c1T + (size_t)s * (2 * D_) + dq) = hv;
    *(float4*)(h1c1T + (size_t)s * (2 * D_) + D_ + dq) = cv;
}

__global__ __launch_bounds__(256) void k_xd(
    const float* __restrict__ inp, const float* __restrict__ Wd,
    const float* __restrict__ bd, float* __restrict__ xd) {
    int id = blockIdx.x * 256 + threadIdx.x;
    const float* row = inp + (size_t)id * F_;
    float s = 0.f;
    #pragma unroll
    for (int f = 0; f < F_; ++f) s += row[f] * Wd[f];
    xd[id] = s + bd[0];
}

// ---------------------------------------------------------------------------
// Decoder scores: grid (B*8); block (b, tp-chunk of 16). Computes xin (redundant
// per chunk; chunk 0 stores xinA), q via table interp, raw scores -> scbuf.
__global__ __launch_bounds__(256) void k_score(
    const float* __restrict__ xd, const float* __restrict__ Wd2,
    const float* __restrict__ qT, const float* __restrict__ v_att,
    const float* __restrict__ ep, const float* __restrict__ ctx_prev,
    float* __restrict__ scbuf, float* __restrict__ xin_all, int t) {
    const int b = blockIdx.x >> 3;
    const int qc = blockIdx.x & 7;
    const int tid = threadIdx.x;
    const int wave = tid >> 6, lane = tid & 63;
    __shared__ float qs[512], vs[512], red[4];
    // ---- xin
    float part = 0.f;
    if (t > 0) {
        const float* cp = ctx_prev + (size_t)b * U_;
        part = cp[tid] * Wd2[tid] + cp[tid + 256] * Wd2[tid + 256];
    }
    #pragma unroll
    for (int off = 32; off; off >>= 1) part += __shfl_xor(part, off);
    if (lane == 0) red[wave] = part;
    __syncthreads();
    const float xin = xd[b * T_ + t] + red[0] + red[1] + red[2] + red[3];
    if (qc == 0 && tid == 0) xin_all[t * B_ + b] = xin;
    // ---- q interp + v stage
    float u = (xin - LO_) * IDT_;
    u = fminf(fmaxf(u, 0.0f), (float)NS_ - 1.001f);
    int i0 = (int)u; float fr = u - (float)i0;
    #pragma unroll
    for (int p = 0; p < 2; ++p) {
        int a = p * 256 + tid;
        float lo = qT[(size_t)i0 * A_ + a];
        float hi = qT[(size_t)(i0 + 1) * A_ + a];
        qs[a] = lo + fr * (hi - lo);
        vs[a] = v_att[a];
    }
    __syncthreads();
    // ---- scores for this chunk (4 waves x 4 tps)
    for (int tpi = wave; tpi < 16; tpi += 4) {
        int tp = qc * 16 + tpi;
        const float* row = ep + ((size_t)b * T_ + tp) * A_;
        float s = 0.f;
        #pragma unroll
        for (int i = 0; i < 8; ++i) {
            int a = lane + 64 * i;
            s += tanh_fast(qs[a] + row[a]) * vs[a];
        }
        #pragma unroll
        for (int off = 32; off; off >>= 1) s += __shfl_xor(s, off);
        if (lane == 0) scbuf[b * T_ + tp] = s;
    }
}

// Softmax (redundant per block) + context slice. grid (B*2), 512 threads.
// Block: b = bid>>1, u-slice of 256. Two tp-groups of 64 each, LDS-combined.
__global__ __launch_bounds__(512) void k_ctx(
    const float* __restrict__ scbuf, const float* __restrict__ enc,
    float* __restrict__ ctx_out) {
    const int b = blockIdx.x >> 1;
    const int u0 = (blockIdx.x & 1) * 256;
    const int tid = threadIdx.x;
    const int wave = tid >> 6, lane = tid & 63;
    __shared__ float w[128], red[4], cpart[256];
    float sv = 0.f;
    if (tid < 128) {
        sv = scbuf[b * T_ + tid];
        float m = sv;
        #pragma unroll
        for (int off = 32; off; off >>= 1) m = fmaxf(m, __shfl_xor(m, off));
        if (lane == 0) red[wave] = m;
    }
    __syncthreads();
    if (tid < 128) {
        float gm = fmaxf(red[0], red[1]);
        float e = __expf(sv - gm);
        w[tid] = e;
        float ss = e;
        #pragma unroll
        for (int off = 32; off; off >>= 1) ss += __shfl_xor(ss, off);
        if (lane == 0) red[2 + wave] = ss;
    }
    __syncthreads();
    const float inv = 1.0f / (red[2] + red[3]);
    const int g = tid >> 8;           // 0/1 -> tp half
    const int u = u0 + (tid & 255);
    const float* base = enc + (size_t)b * (T_ * U_) + u;
    float acc = 0.f;
    const int tp0 = g * 64;
    #pragma unroll 8
    for (int tp = tp0; tp < tp0 + 64; ++tp) acc += w[tp] * base[(size_t)tp * U_];
    if (g == 1) cpart[tid & 255] = acc;
    __syncthreads();
    if (g == 0) ctx_out[(size_t)b * U_ + u] = (acc + cpart[tid & 255]) * inv;
}

// ---------------------------------------------------------------------------
// Final LSTM split-source GEMM: zp[s][i][n], s=0: h_f@Uf; s=1: gathered-ctx@Wf2.
// BM=32,BN=64,BK=16,TM=2,TN=4. grid (2048/64, 256/32, 2) = (32,8,2) = 512 blocks.
__global__ __launch_bounds__(256) void k_fstep(
    const float* __restrict__ h_f, const float* __restrict__ ctx_all,
    const float* __restrict__ Uf, const float* __restrict__ Wf2,
    float* __restrict__ zp, int j) {
    constexpr int BK = 16;
    __shared__ float As[BK][36];
    __shared__ float Bs[BK][64];
    const int s = blockIdx.z;
    const int n0 = blockIdx.x * 64, m0 = blockIdx.y * 32;
    const int tid = threadIdx.x, tx = tid & 15, ty = tid >> 4;
    // A stage: 32x16 = 128 float4, tid<128
    const int am = tid >> 2, ak4 = (tid & 3) * 4;
    const float* arow = nullptr;
    if (tid < 128) {
        int i = m0 + am;
        if (s == 0) arow = h_f + (size_t)i * D_;
        else {
            int tt = i >> 1, bb = ((i & 1) << 7) + j;
            arow = ctx_all + ((size_t)tt * B_ + bb) * U_;
        }
    }
    const float* Bmat = (s == 0) ? Uf : Wf2;
    const int bk = tid >> 4, bn4 = (tid & 15) * 4;
    const float* bp = Bmat + (size_t)bk * G_ + n0 + bn4;
    float4 ar = (tid < 128) ? *(const float4*)(arow + ak4) : make_float4(0, 0, 0, 0);
    float4 br = *(const float4*)(bp);
    float acc[2][4] = {};
    for (int k0 = 0; k0 < 512; k0 += BK) {
        __syncthreads();
        if (tid < 128) {
            As[ak4 + 0][am] = ar.x; As[ak4 + 1][am] = ar.y;
            As[ak4 + 2][am] = ar.z; As[ak4 + 3][am] = ar.w;
        }
        *(float4*)&Bs[bk][bn4] = br;
        __syncthreads();
        if (k0 + BK < 512) {
            if (tid < 128) ar = *(const float4*)(arow + k0 + BK + ak4);
            br = *(const float4*)(bp + (size_t)(k0 + BK) * G_);
        }
        #pragma unroll
        for (int kk = 0; kk < BK; ++kk) {
            float2 a = *(const float2*)&As[kk][ty * 2];
            float4 b = *(const float4*)&Bs[kk][tx * 4];
            acc[0][0] += a.x * b.x; acc[0][1] += a.x * b.y; acc[0][2] += a.x * b.z; acc[0][3] += a.x * b.w;
            acc[1][0] += a.y * b.x; acc[1][1] += a.y * b.y; acc[1][2] += a.y * b.z; acc[1][3] += a.y * b.w;
        }
    }
    float* dst = zp + (size_t)s * (B_ * G_);
    #pragma unroll
    for (int im = 0; im < 2; ++im)
        *(float4*)(dst + (size_t)(m0 + ty * 2 + im) * G_ + n0 + tx * 4) =
            make_float4(acc[im][0], acc[im][1], acc[im][2], acc[im][3]);
}

// Final gates: z = zp0+zp1 + interp(zhT) + bf; update h_f,c_f; write out[i][j].
__global__ __launch_bounds__(256) void k_fgate(
    const float* __restrict__ zp, const float* __restrict__ zhT,
    const float* __restrict__ xinA, const float* __restrict__ bf,
    float* __restrict__ h_f, float* __restrict__ c_f,
    float* __restrict__ out, int j) {
    const int i = blockIdx.x, tid = threadIdx.x;
    const int tt = i >> 1, bb = ((i & 1) << 7) + j;
    float xin = xinA[tt * B_ + bb];
    float u = (xin - LO_) * IDT_;
    u = fminf(fmaxf(u, 0.0f), (float)NS_ - 1.001f);
    int i0 = (int)u; float fr = u - (float)i0;
    const float* zh0 = zhT + (size_t)i0 * G_;
    const float* zh1 = zh0 + G_;
    const float* z0 = zp + (size_t)i * G_;
    const float* z1 = zp + (size_t)(B_ + i) * G_;
    #pragma unroll
    for (int p = 0; p < 2; ++p) {
        int d = p * 256 + tid;
        float zg4[4];
        #pragma unroll
        for (int g = 0; g < 4; ++g) {
            int col = g * 512 + d;
            float lo = zh0[col];
            zg4[g] = z0[col] + z1[col] + lo + fr * (zh1[col] - lo) + bf[col];
        }
        float c_old = c_f[(size_t)i * D_ + d];
        float cn = sigf(zg4[1]) * c_old + sigf(zg4[0]) * tanh_fast(zg4[2]);
        float hn = sigf(zg4[3]) * tanh_fast(cn);
        c_f[(size_t)i * D_ + d] = cn;
        h_f[(size_t)i * D_ + d] = hn;
        out[((size_t)i * T_ + j) * D_ + d] = hn;
    }
}

// ---------------------------------------------------------------------------
extern "C" void kernel_launch(void* const* d_in, const int* in_sizes, int n_in,
                              void* d_out, int out_size, void* d_ws, size_t ws_size,
                              hipStream_t stream) {
    const float* inputs = (const float*)d_in[0];
    const float* enc    = (const float*)d_in[1];
    const float* Wd     = (const float*)d_in[2];
    const float* bd     = (const float*)d_in[3];
    const float* W0     = (const float*)d_in[4];
    const float* b0     = (const float*)d_in[6];
    const float* W1     = (const float*)d_in[7];
    const float* b1     = (const float*)d_in[9];
    const float* Wq     = (const float*)d_in[10];
    const float* Wk     = (const float*)d_in[11];
    const float* v_att  = (const float*)d_in[12];
    const float* Wf     = (const float*)d_in[13];
    const float* Uf     = (const float*)d_in[14];
    const float* bf     = (const float*)d_in[15];
    float* out = (float*)d_out;

    float* ws = (float*)d_ws;
    float* ep      = ws;                          // 16,777,216  [B][T][A]
    float* ctx_all = ep + (size_t)16777216;       // 16,777,216  [T][B][U]
    float* qT      = ctx_all + (size_t)16777216;  //  2,097,152  [NS][A]
    float* zhT     = qT + (size_t)2097152;        //  8,388,608  [NS][G]
    float* h0T     = zhT + (size_t)8388608;       //  2,097,152  [NS][D]
    float* h1c1T   = h0T + (size_t)2097152;       //  4,194,304  [NS][2D]
    float* xd      = h1c1T + (size_t)4194304;     //     32,768  [B][T]
    float* xinA    = xd + 32768;                  //     32,768  [T][B]
    float* zp      = xinA + 32768;                //  1,048,576  [2][B][G]
    float* h_f     = zp + 1048576;                //    131,072
    float* c_f     = h_f + 131072;                //    131,072
    float* scbuf   = c_f + 131072;                //     32,768  [B][T]
    float* z1T     = ep;                          // alias (consumed pre-encproj)

    // ---- tables (one-time per launch)
    k_h0build<<<dim3(NS_ * D_ / 1024), 256, 0, stream>>>(W0, b0, h0T);
    k_gemm128<<<dim3(G_ / 128, NS_ / 128), 256, 0, stream>>>(h0T, D_, W1, G_, z1T, G_, D_);
    k_gates1<<<dim3(NS_ * D_ / 1024), 256, 0, stream>>>(z1T, b1, h1c1T);
    k_gemm128<<<dim3(A_ / 128, NS_ / 128), 256, 0, stream>>>(h1c1T, 2 * D_, Wq, A_, qT, A_, 2 * D_);
    k_gemm128<<<dim3(G_ / 128, NS_ / 128), 256, 0, stream>>>(h1c1T, 2 * D_, Wf, G_, zhT, G_, D_);
    k_xd<<<dim3(B_ * T_ / 256), 256, 0, stream>>>(inputs, Wd, bd, xd);
    k_gemm128<<<dim3(A_ / 128, (B_ * T_) / 128), 256, 0, stream>>>(enc, U_, Wk, A_, ep, A_, U_);

    hipMemsetAsync(h_f, 0, (size_t)B_ * D_ * sizeof(float), stream);
    hipMemsetAsync(c_f, 0, (size_t)B_ * D_ * sizeof(float), stream);

    // ---- decoder loop (2 kernels/step: scores, then softmax+context)
    for (int t = 0; t < T_; ++t) {
        const float* ctx_prev = ctx_all + (size_t)((t == 0) ? 0 : (t - 1)) * B_ * U_;
        float* ctx_t = ctx_all + (size_t)t * B_ * U_;
        k_score<<<dim3(B_ * 8), 256, 0, stream>>>(xd, Wd + F_, qT, v_att, ep,
                                                  ctx_prev, scbuf, xinA, t);
        k_ctx<<<dim3(B_ * 2), 512, 0, stream>>>(scbuf, enc, ctx_t);
    }
    // ---- final LSTM loop
    const float* Wf2 = Wf + (size_t)D_ * G_;
    for (int j = 0; j < T_; ++j) {
        k_fstep<<<dim3(G_ / 64, B_ / 32, 2), 256, 0, stream>>>(h_f, ctx_all, Uf, Wf2, zp, j);
        k_fgate<<<dim3(B_), 256, 0, stream>>>(zp, zhT, xinA, bf, h_f, c_f, out, j);
    }
}

// Round 4
// 6982.978 us; speedup vs baseline: 2.9788x; 1.0848x over previous
//
#include <hip/hip_runtime.h>

// Problem constants
constexpr int B_ = 256;
constexpr int T_ = 128;
constexpr int F_ = 32;
constexpr int U_ = 512;   // U_ENC
constexpr int D_ = 512;
constexpr int A_ = 512;
constexpr int G_ = 2048;  // 4*D

// xin lookup table
constexpr int   NS_   = 4096;
constexpr float LO_   = -16.0f;
constexpr float IDT_  = 128.0f;   // NS / 32

__device__ __forceinline__ float sigf(float x) { return 1.0f / (1.0f + __expf(-x)); }
__device__ __forceinline__ float tanh_fast(float x) {
    return 2.0f / (1.0f + __expf(-2.0f * x)) - 1.0f;
}
__device__ __forceinline__ float bflo(unsigned int u) { return __uint_as_float(u << 16); }
__device__ __forceinline__ float bfhi(unsigned int u) { return __uint_as_float(u & 0xffff0000u); }

// ---------------------------------------------------------------------------
// Generic f32 GEMM: C[M,N] = A[M,K]@B[K,N].  BM=BN=128, BK=16, TM=TN=8.
__global__ __launch_bounds__(256) void k_gemm128(
    const float* __restrict__ A, int lda,
    const float* __restrict__ Bm, int ldb,
    float* __restrict__ C, int ldc, int K) {
    constexpr int BK = 16;
    __shared__ float As[BK][132];
    __shared__ float Bs[BK][128];
    const int tid = threadIdx.x;
    const int tx = tid & 15, ty = tid >> 4;
    const int m0 = blockIdx.y * 128, n0 = blockIdx.x * 128;
    const int am0 = tid >> 2,          ak40 = (tid & 3) * 4;
    const int am1 = (256 + tid) >> 2,  ak41 = ((256 + tid) & 3) * 4;
    const int bk0 = tid >> 5,          bn40 = (tid & 31) * 4;
    const int bk1 = (256 + tid) >> 5,  bn41 = ((256 + tid) & 31) * 4;
    const float* a0p = A + (size_t)(m0 + am0) * lda + ak40;
    const float* a1p = A + (size_t)(m0 + am1) * lda + ak41;
    const float* b0p = Bm + (size_t)bk0 * ldb + n0 + bn40;
    const float* b1p = Bm + (size_t)bk1 * ldb + n0 + bn41;
    float4 ar0 = *(const float4*)(a0p);
    float4 ar1 = *(const float4*)(a1p);
    float4 br0 = *(const float4*)(b0p);
    float4 br1 = *(const float4*)(b1p);
    float acc[8][8] = {};
    for (int k0 = 0; k0 < K; k0 += BK) {
        __syncthreads();
        As[ak40 + 0][am0] = ar0.x; As[ak40 + 1][am0] = ar0.y;
        As[ak40 + 2][am0] = ar0.z; As[ak40 + 3][am0] = ar0.w;
        As[ak41 + 0][am1] = ar1.x; As[ak41 + 1][am1] = ar1.y;
        As[ak41 + 2][am1] = ar1.z; As[ak41 + 3][am1] = ar1.w;
        *(float4*)&Bs[bk0][bn40] = br0;
        *(float4*)&Bs[bk1][bn41] = br1;
        __syncthreads();
        if (k0 + BK < K) {
            ar0 = *(const float4*)(a0p + k0 + BK);
            ar1 = *(const float4*)(a1p + k0 + BK);
            br0 = *(const float4*)(b0p + (size_t)(k0 + BK) * ldb);
            br1 = *(const float4*)(b1p + (size_t)(k0 + BK) * ldb);
        }
        #pragma unroll
        for (int kk = 0; kk < BK; ++kk) {
            float a[8], b[8];
            *(float4*)&a[0] = *(const float4*)&As[kk][ty * 8];
            *(float4*)&a[4] = *(const float4*)&As[kk][ty * 8 + 4];
            *(float4*)&b[0] = *(const float4*)&Bs[kk][tx * 8];
            *(float4*)&b[4] = *(const float4*)&Bs[kk][tx * 8 + 4];
            #pragma unroll
            for (int im = 0; im < 8; ++im)
                #pragma unroll
                for (int in = 0; in < 8; ++in)
                    acc[im][in] += a[im] * b[in];
        }
    }
    #pragma unroll
    for (int im = 0; im < 8; ++im) {
        float* crow = C + (size_t)(m0 + ty * 8 + im) * ldc + n0 + tx * 8;
        *(float4*)(crow)     = make_float4(acc[im][0], acc[im][1], acc[im][2], acc[im][3]);
        *(float4*)(crow + 4) = make_float4(acc[im][4], acc[im][5], acc[im][6], acc[im][7]);
    }
}

// ---------------------------------------------------------------------------
__global__ __launch_bounds__(256) void k_h0build(
    const float* __restrict__ W0, const float* __restrict__ b0,
    float* __restrict__ h0T) {
    int idx4 = blockIdx.x * 256 + threadIdx.x;
    int s = idx4 >> 7, kq = (idx4 & 127) * 4;
    float sv = LO_ + (float)s * (1.0f / IDT_);
    float4 o;
    float* po = &o.x;
    #pragma unroll
    for (int jj = 0; jj < 4; ++jj) {
        int k = kq + jj;
        float zi = sv * W0[k] + b0[k];
        float zg = sv * W0[1024 + k] + b0[1024 + k];
        float zo = sv * W0[1536 + k] + b0[1536 + k];
        float c0 = sigf(zi) * tanh_fast(zg);
        po[jj] = sigf(zo) * tanh_fast(c0);
    }
    *(float4*)(h0T + (size_t)s * D_ + kq) = o;
}

__global__ __launch_bounds__(256) void k_gates1(
    const float* __restrict__ z1T, const float* __restrict__ b1,
    float* __restrict__ h1c1T) {
    int idx4 = blockIdx.x * 256 + threadIdx.x;
    int s = idx4 >> 7, dq = (idx4 & 127) * 4;
    const float* z = z1T + (size_t)s * G_;
    float4 hv, cv;
    float* ph = &hv.x; float* pc = &cv.x;
    #pragma unroll
    for (int jj = 0; jj < 4; ++jj) {
        int d = dq + jj;
        float zi = z[d] + b1[d];
        float zg = z[1024 + d] + b1[1024 + d];
        float zo = z[1536 + d] + b1[1536 + d];
        float c1 = sigf(zi) * tanh_fast(zg);
        pc[jj] = c1;
        ph[jj] = sigf(zo) * tanh_fast(c1);
    }
    *(float4*)(h1c1T + (size_t)s * (2 * D_) + dq) = hv;
    *(float4*)(h1c1T + (size_t)s * (2 * D_) + D_ + dq) = cv;
}

__global__ __launch_bounds__(256) void k_xd(
    const float* __restrict__ inp, const float* __restrict__ Wd,
    const float* __restrict__ bd, float* __restrict__ xd) {
    int id = blockIdx.x * 256 + threadIdx.x;
    const float* row = inp + (size_t)id * F_;
    float s = 0.f;
    #pragma unroll
    for (int f = 0; f < F_; ++f) s += row[f] * Wd[f];
    xd[id] = s + bd[0];
}

// f32 -> bf16 (round-to-nearest-even), 8 elems/thread
__global__ __launch_bounds__(256) void k_cvt_bf16(
    const float* __restrict__ src, unsigned short* __restrict__ dst) {
    size_t i = ((size_t)blockIdx.x * 256 + threadIdx.x) * 8;
    float4 a = *(const float4*)(src + i);
    float4 b = *(const float4*)(src + i + 4);
    float v[8] = {a.x, a.y, a.z, a.w, b.x, b.y, b.z, b.w};
    unsigned int pk[4];
    #pragma unroll
    for (int j = 0; j < 4; ++j) {
        unsigned int u0 = __float_as_uint(v[2 * j]);
        unsigned int u1 = __float_as_uint(v[2 * j + 1]);
        u0 = (u0 + 0x7fffu + ((u0 >> 16) & 1u)) >> 16;
        u1 = (u1 + 0x7fffu + ((u1 >> 16) & 1u)) >> 16;
        pk[j] = u0 | (u1 << 16);
    }
    *(uint4*)(dst + i) = make_uint4(pk[0], pk[1], pk[2], pk[3]);
}

// xinA[0][b] = xd[b][0]
__global__ __launch_bounds__(256) void k_init_xin(
    const float* __restrict__ xd, float* __restrict__ xinA) {
    int b = threadIdx.x;
    xinA[b] = xd[b * T_];
}

// ---------------------------------------------------------------------------
// Fused decoder step. One block per b, 512 threads (8 waves).
// Phase 1: scores (wave per tp, 8 bf16/lane); Phase 2: softmax; Phase 3: ctx
// (split tp halves); Phase 4: xin[t+1]. Reads ep/enc as bf16.
__global__ __launch_bounds__(512) void k_step(
    const float* __restrict__ xd, const float* __restrict__ Wd2,
    const float* __restrict__ qT, const float* __restrict__ v_att,
    const unsigned short* __restrict__ ep_bf,
    const unsigned short* __restrict__ enc_bf,
    float* __restrict__ ctx_t, float* __restrict__ xinA, int t) {
    const int b = blockIdx.x;
    const int tid = threadIdx.x;
    const int wave = tid >> 6, lane = tid & 63;
    __shared__ float sc[128];
    __shared__ float red[16];
    __shared__ float cpart[512];
    // ---- q interp into registers (redundant per wave; lane owns a = lane*8..+7)
    const float xin = xinA[t * B_ + b];
    float uu = (xin - LO_) * IDT_;
    uu = fminf(fmaxf(uu, 0.0f), (float)NS_ - 1.001f);
    const int i0 = (int)uu;
    const float fr = uu - (float)i0;
    float qs[8], vs[8];
    {
        const float* qlo = qT + (size_t)i0 * A_ + lane * 8;
        const float* qhi = qlo + A_;
        const float* vp  = v_att + lane * 8;
        float4 l0 = *(const float4*)(qlo);
        float4 l1 = *(const float4*)(qlo + 4);
        float4 h0 = *(const float4*)(qhi);
        float4 h1 = *(const float4*)(qhi + 4);
        float4 v0 = *(const float4*)(vp);
        float4 v1 = *(const float4*)(vp + 4);
        const float* pl0 = &l0.x; const float* pl1 = &l1.x;
        const float* ph0 = &h0.x; const float* ph1 = &h1.x;
        const float* pv0 = &v0.x; const float* pv1 = &v1.x;
        #pragma unroll
        for (int j = 0; j < 4; ++j) {
            qs[j]     = pl0[j] + fr * (ph0[j] - pl0[j]);
            qs[4 + j] = pl1[j] + fr * (ph1[j] - pl1[j]);
            vs[j]     = pv0[j];
            vs[4 + j] = pv1[j];
        }
    }
    // ---- scores: wave handles tp = wave + 8k
    #pragma unroll 2
    for (int k = 0; k < 16; ++k) {
        const int tp = wave + 8 * k;
        const unsigned short* row = ep_bf + ((size_t)b * T_ + tp) * A_ + lane * 8;
        uint4 rv = *(const uint4*)row;
        unsigned int uw[4] = {rv.x, rv.y, rv.z, rv.w};
        float s = 0.f;
        #pragma unroll
        for (int q2 = 0; q2 < 4; ++q2) {
            s += tanh_fast(qs[2 * q2]     + bflo(uw[q2])) * vs[2 * q2];
            s += tanh_fast(qs[2 * q2 + 1] + bfhi(uw[q2])) * vs[2 * q2 + 1];
        }
        #pragma unroll
        for (int off = 32; off; off >>= 1) s += __shfl_xor(s, off);
        if (lane == 0) sc[tp] = s;
    }
    __syncthreads();
    // ---- softmax over sc[128] (tid < 128), leaves unnormalized exp in sc
    float sv = 0.f;
    if (tid < 128) {
        sv = sc[tid];
        float m = sv;
        #pragma unroll
        for (int off = 32; off; off >>= 1) m = fmaxf(m, __shfl_xor(m, off));
        if (lane == 0) red[wave] = m;
    }
    __syncthreads();
    if (tid < 128) {
        const float gm = fmaxf(red[0], red[1]);
        const float e = __expf(sv - gm);
        sc[tid] = e;
        float ss = e;
        #pragma unroll
        for (int off = 32; off; off >>= 1) ss += __shfl_xor(ss, off);
        if (lane == 0) red[2 + wave] = ss;
    }
    __syncthreads();
    const float inv = 1.0f / (red[2] + red[3]);
    // ---- context: g = tp-half, idx covers u pairs
    const int g = tid >> 8, idx = tid & 255;
    const int u2 = idx * 2;
    float accx = 0.f, accy = 0.f;
    {
        const unsigned short* base = enc_bf + ((size_t)b * T_ + g * 64) * U_ + u2;
        const float* wp = &sc[g * 64];
        #pragma unroll 8
        for (int tp = 0; tp < 64; ++tp) {
            unsigned int w2 = *(const unsigned int*)(base + (size_t)tp * U_);
            float wgt = wp[tp];
            accx += wgt * bflo(w2);
            accy += wgt * bfhi(w2);
        }
    }
    if (g == 1) { cpart[u2] = accx; cpart[u2 + 1] = accy; }
    __syncthreads();
    float xpart = 0.f;
    if (g == 0) {
        const float c0 = (accx + cpart[u2]) * inv;
        const float c1 = (accy + cpart[u2 + 1]) * inv;
        *(float2*)(ctx_t + (size_t)b * U_ + u2) = make_float2(c0, c1);
        xpart = c0 * Wd2[u2] + c1 * Wd2[u2 + 1];
    }
    // ---- xin for t+1
    #pragma unroll
    for (int off = 32; off; off >>= 1) xpart += __shfl_xor(xpart, off);
    if (lane == 0) red[8 + wave] = xpart;
    __syncthreads();
    if (tid == 0 && t + 1 < T_) {
        const float s = red[8] + red[9] + red[10] + red[11];
        xinA[(t + 1) * B_ + b] = xd[b * T_ + (t + 1)] + s;
    }
}

// ---------------------------------------------------------------------------
// Final LSTM split-source GEMM: zp[s][i][n], s=0: h_f@Uf; s=1: gathered-ctx@Wf2.
// BM=32,BN=64,BK=16,TM=2,TN=4. grid (32,8,2) = 512 blocks.
__global__ __launch_bounds__(256) void k_fstep(
    const float* __restrict__ h_f, const float* __restrict__ ctx_all,
    const float* __restrict__ Uf, const float* __restrict__ Wf2,
    float* __restrict__ zp, int j) {
    constexpr int BK = 16;
    __shared__ float As[BK][36];
    __shared__ float Bs[BK][64];
    const int s = blockIdx.z;
    const int n0 = blockIdx.x * 64, m0 = blockIdx.y * 32;
    const int tid = threadIdx.x, tx = tid & 15, ty = tid >> 4;
    const int am = tid >> 2, ak4 = (tid & 3) * 4;
    const float* arow = nullptr;
    if (tid < 128) {
        int i = m0 + am;
        if (s == 0) arow = h_f + (size_t)i * D_;
        else {
            int tt = i >> 1, bb = ((i & 1) << 7) + j;
            arow = ctx_all + ((size_t)tt * B_ + bb) * U_;
        }
    }
    const float* Bmat = (s == 0) ? Uf : Wf2;
    const int bk = tid >> 4, bn4 = (tid & 15) * 4;
    const float* bp = Bmat + (size_t)bk * G_ + n0 + bn4;
    float4 ar = (tid < 128) ? *(const float4*)(arow + ak4) : make_float4(0, 0, 0, 0);
    float4 br = *(const float4*)(bp);
    float acc[2][4] = {};
    for (int k0 = 0; k0 < 512; k0 += BK) {
        __syncthreads();
        if (tid < 128) {
            As[ak4 + 0][am] = ar.x; As[ak4 + 1][am] = ar.y;
            As[ak4 + 2][am] = ar.z; As[ak4 + 3][am] = ar.w;
        }
        *(float4*)&Bs[bk][bn4] = br;
        __syncthreads();
        if (k0 + BK < 512) {
            if (tid < 128) ar = *(const float4*)(arow + k0 + BK + ak4);
            br = *(const float4*)(bp + (size_t)(k0 + BK) * G_);
        }
        #pragma unroll
        for (int kk = 0; kk < BK; ++kk) {
            float2 a = *(const float2*)&As[kk][ty * 2];
            float4 b = *(const float4*)&Bs[kk][tx * 4];
            acc[0][0] += a.x * b.x; acc[0][1] += a.x * b.y; acc[0][2] += a.x * b.z; acc[0][3] += a.x * b.w;
            acc[1][0] += a.y * b.x; acc[1][1] += a.y * b.y; acc[1][2] += a.y * b.z; acc[1][3] += a.y * b.w;
        }
    }
    float* dst = zp + (size_t)s * (B_ * G_);
    #pragma unroll
    for (int im = 0; im < 2; ++im)
        *(float4*)(dst + (size_t)(m0 + ty * 2 + im) * G_ + n0 + tx * 4) =
            make_float4(acc[im][0], acc[im][1], acc[im][2], acc[im][3]);
}

// Final gates: z = zp0+zp1 + interp(zhT) + bf; update h_f,c_f; write out[i][j].
__global__ __launch_bounds__(256) void k_fgate(
    const float* __restrict__ zp, const float* __restrict__ zhT,
    const float* __restrict__ xinA, const float* __restrict__ bf,
    float* __restrict__ h_f, float* __restrict__ c_f,
    float* __restrict__ out, int j) {
    const int i = blockIdx.x, tid = threadIdx.x;
    const int tt = i >> 1, bb = ((i & 1) << 7) + j;
    float xin = xinA[tt * B_ + bb];
    float u = (xin - LO_) * IDT_;
    u = fminf(fmaxf(u, 0.0f), (float)NS_ - 1.001f);
    int i0 = (int)u; float fr = u - (float)i0;
    const float* zh0 = zhT + (size_t)i0 * G_;
    const float* zh1 = zh0 + G_;
    const float* z0 = zp + (size_t)i * G_;
    const float* z1 = zp + (size_t)(B_ + i) * G_;
    #pragma unroll
    for (int p = 0; p < 2; ++p) {
        int d = p * 256 + tid;
        float zg4[4];
        #pragma unroll
        for (int g = 0; g < 4; ++g) {
            int col = g * 512 + d;
            float lo = zh0[col];
            zg4[g] = z0[col] + z1[col] + lo + fr * (zh1[col] - lo) + bf[col];
        }
        float c_old = c_f[(size_t)i * D_ + d];
        float cn = sigf(zg4[1]) * c_old + sigf(zg4[0]) * tanh_fast(zg4[2]);
        float hn = sigf(zg4[3]) * tanh_fast(cn);
        c_f[(size_t)i * D_ + d] = cn;
        h_f[(size_t)i * D_ + d] = hn;
        out[((size_t)i * T_ + j) * D_ + d] = hn;
    }
}

// ---------------------------------------------------------------------------
extern "C" void kernel_launch(void* const* d_in, const int* in_sizes, int n_in,
                              void* d_out, int out_size, void* d_ws, size_t ws_size,
                              hipStream_t stream) {
    const float* inputs = (const float*)d_in[0];
    const float* enc    = (const float*)d_in[1];
    const float* Wd     = (const float*)d_in[2];
    const float* bd     = (const float*)d_in[3];
    const float* W0     = (const float*)d_in[4];
    const float* b0     = (const float*)d_in[6];
    const float* W1     = (const float*)d_in[7];
    const float* b1     = (const float*)d_in[9];
    const float* Wq     = (const float*)d_in[10];
    const float* Wk     = (const float*)d_in[11];
    const float* v_att  = (const float*)d_in[12];
    const float* Wf     = (const float*)d_in[13];
    const float* Uf     = (const float*)d_in[14];
    const float* bf     = (const float*)d_in[15];
    float* out = (float*)d_out;

    float* ws = (float*)d_ws;
    // layout (floats)
    unsigned short* ep_bf  = (unsigned short*)ws;                 //  8,388,608 f (16.7M bf16)
    unsigned short* enc_bf = (unsigned short*)(ws + 8388608);     //  8,388,608 f
    float* ctx_all = ws + (size_t)16777216;                       // 16,777,216 f  [T][B][U]
    float* qT      = ctx_all + (size_t)16777216;                  //  2,097,152 f
    float* zhT     = qT + (size_t)2097152;                        //  8,388,608 f
    float* h0T     = zhT + (size_t)8388608;                       //  2,097,152 f
    float* h1c1T   = h0T + (size_t)2097152;                       //  4,194,304 f
    float* xd      = h1c1T + (size_t)4194304;                     //     32,768 f
    float* xinA    = xd + 32768;                                  //     33,024 f
    float* zp      = xinA + 33024;                                //  1,048,576 f
    float* h_f     = zp + 1048576;                                //    131,072 f
    float* c_f     = h_f + 131072;                                //    131,072 f
    // z1T and the f32 ep temp alias ctx_all (both fully consumed before the
    // decoder loop writes any ctx).
    float* z1T    = ctx_all;
    float* ep_tmp = ctx_all;

    // ---- tables (one-time per launch)
    k_h0build<<<dim3(NS_ * D_ / 1024), 256, 0, stream>>>(W0, b0, h0T);
    k_gemm128<<<dim3(G_ / 128, NS_ / 128), 256, 0, stream>>>(h0T, D_, W1, G_, z1T, G_, D_);
    k_gates1<<<dim3(NS_ * D_ / 1024), 256, 0, stream>>>(z1T, b1, h1c1T);
    k_gemm128<<<dim3(A_ / 128, NS_ / 128), 256, 0, stream>>>(h1c1T, 2 * D_, Wq, A_, qT, A_, 2 * D_);
    k_gemm128<<<dim3(G_ / 128, NS_ / 128), 256, 0, stream>>>(h1c1T, 2 * D_, Wf, G_, zhT, G_, D_);
    // enc projection into f32 temp (overwrites z1T alias — already consumed)
    k_gemm128<<<dim3(A_ / 128, (B_ * T_) / 128), 256, 0, stream>>>(enc, U_, Wk, A_, ep_tmp, A_, U_);
    k_cvt_bf16<<<dim3(8192), 256, 0, stream>>>(ep_tmp, ep_bf);
    k_cvt_bf16<<<dim3(8192), 256, 0, stream>>>(enc, enc_bf);
    k_xd<<<dim3(B_ * T_ / 256), 256, 0, stream>>>(inputs, Wd, bd, xd);
    k_init_xin<<<dim3(1), 256, 0, stream>>>(xd, xinA);

    hipMemsetAsync(h_f, 0, (size_t)B_ * D_ * sizeof(float), stream);
    hipMemsetAsync(c_f, 0, (size_t)B_ * D_ * sizeof(float), stream);

    // ---- decoder loop (1 fused kernel per step)
    for (int t = 0; t < T_; ++t) {
        float* ctx_t = ctx_all + (size_t)t * B_ * U_;
        k_step<<<dim3(B_), 512, 0, stream>>>(xd, Wd + F_, qT, v_att, ep_bf, enc_bf,
                                             ctx_t, xinA, t);
    }
    // ---- final LSTM loop
    const float* Wf2 = Wf + (size_t)D_ * G_;
    for (int j = 0; j < T_; ++j) {
        k_fstep<<<dim3(G_ / 64, B_ / 32, 2), 256, 0, stream>>>(h_f, ctx_all, Uf, Wf2, zp, j);
        k_fgate<<<dim3(B_), 256, 0, stream>>>(zp, zhT, xinA, bf, h_f, c_f, out, j);
    }
}

// Round 5
// 6595.387 us; speedup vs baseline: 3.1539x; 1.0588x over previous
//
#include <hip/hip_runtime.h>

// Problem constants
constexpr int B_ = 256;
constexpr int T_ = 128;
constexpr int F_ = 32;
constexpr int U_ = 512;   // U_ENC
constexpr int D_ = 512;
constexpr int A_ = 512;
constexpr int G_ = 2048;  // 4*D

// xin lookup tables: qT/zhT grid (fine), s_tab grid (coarse)
constexpr int   NS_   = 2048;
constexpr float LO_   = -8.0f;
constexpr float IDT_  = 128.0f;   // spacing 1/128 over [-8,8)
constexpr int   KS_   = 128;
constexpr float LOS_  = -8.0f;
constexpr float IDTS_ = 8.0f;     // spacing 1/8 over [-8,8); s-grid k <-> qT row 16k

__device__ __forceinline__ float sigf(float x) { return 1.0f / (1.0f + __expf(-x)); }
__device__ __forceinline__ float tanh_fast(float x) {
    return 2.0f / (1.0f + __expf(-2.0f * x)) - 1.0f;
}
__device__ __forceinline__ float bflo(unsigned int u) { return __uint_as_float(u << 16); }
__device__ __forceinline__ float bfhi(unsigned int u) { return __uint_as_float(u & 0xffff0000u); }

// ---------------------------------------------------------------------------
// Generic f32 GEMM: C[M,N] = A[M,K]@B[K,N].  BM=BN=128, BK=16, TM=TN=8.
__global__ __launch_bounds__(256) void k_gemm128(
    const float* __restrict__ A, int lda,
    const float* __restrict__ Bm, int ldb,
    float* __restrict__ C, int ldc, int K) {
    constexpr int BK = 16;
    __shared__ float As[BK][132];
    __shared__ float Bs[BK][128];
    const int tid = threadIdx.x;
    const int tx = tid & 15, ty = tid >> 4;
    const int m0 = blockIdx.y * 128, n0 = blockIdx.x * 128;
    const int am0 = tid >> 2,          ak40 = (tid & 3) * 4;
    const int am1 = (256 + tid) >> 2,  ak41 = ((256 + tid) & 3) * 4;
    const int bk0 = tid >> 5,          bn40 = (tid & 31) * 4;
    const int bk1 = (256 + tid) >> 5,  bn41 = ((256 + tid) & 31) * 4;
    const float* a0p = A + (size_t)(m0 + am0) * lda + ak40;
    const float* a1p = A + (size_t)(m0 + am1) * lda + ak41;
    const float* b0p = Bm + (size_t)bk0 * ldb + n0 + bn40;
    const float* b1p = Bm + (size_t)bk1 * ldb + n0 + bn41;
    float4 ar0 = *(const float4*)(a0p);
    float4 ar1 = *(const float4*)(a1p);
    float4 br0 = *(const float4*)(b0p);
    float4 br1 = *(const float4*)(b1p);
    float acc[8][8] = {};
    for (int k0 = 0; k0 < K; k0 += BK) {
        __syncthreads();
        As[ak40 + 0][am0] = ar0.x; As[ak40 + 1][am0] = ar0.y;
        As[ak40 + 2][am0] = ar0.z; As[ak40 + 3][am0] = ar0.w;
        As[ak41 + 0][am1] = ar1.x; As[ak41 + 1][am1] = ar1.y;
        As[ak41 + 2][am1] = ar1.z; As[ak41 + 3][am1] = ar1.w;
        *(float4*)&Bs[bk0][bn40] = br0;
        *(float4*)&Bs[bk1][bn41] = br1;
        __syncthreads();
        if (k0 + BK < K) {
            ar0 = *(const float4*)(a0p + k0 + BK);
            ar1 = *(const float4*)(a1p + k0 + BK);
            br0 = *(const float4*)(b0p + (size_t)(k0 + BK) * ldb);
            br1 = *(const float4*)(b1p + (size_t)(k0 + BK) * ldb);
        }
        #pragma unroll
        for (int kk = 0; kk < BK; ++kk) {
            float a[8], b[8];
            *(float4*)&a[0] = *(const float4*)&As[kk][ty * 8];
            *(float4*)&a[4] = *(const float4*)&As[kk][ty * 8 + 4];
            *(float4*)&b[0] = *(const float4*)&Bs[kk][tx * 8];
            *(float4*)&b[4] = *(const float4*)&Bs[kk][tx * 8 + 4];
            #pragma unroll
            for (int im = 0; im < 8; ++im)
                #pragma unroll
                for (int in = 0; in < 8; ++in)
                    acc[im][in] += a[im] * b[in];
        }
    }
    #pragma unroll
    for (int im = 0; im < 8; ++im) {
        float* crow = C + (size_t)(m0 + ty * 8 + im) * ldc + n0 + tx * 8;
        *(float4*)(crow)     = make_float4(acc[im][0], acc[im][1], acc[im][2], acc[im][3]);
        *(float4*)(crow + 4) = make_float4(acc[im][4], acc[im][5], acc[im][6], acc[im][7]);
    }
}

// ---------------------------------------------------------------------------
__global__ __launch_bounds__(256) void k_h0build(
    const float* __restrict__ W0, const float* __restrict__ b0,
    float* __restrict__ h0T) {
    int idx4 = blockIdx.x * 256 + threadIdx.x;
    int s = idx4 >> 7, kq = (idx4 & 127) * 4;
    float sv = LO_ + (float)s * (1.0f / IDT_);
    float4 o;
    float* po = &o.x;
    #pragma unroll
    for (int jj = 0; jj < 4; ++jj) {
        int k = kq + jj;
        float zi = sv * W0[k] + b0[k];
        float zg = sv * W0[1024 + k] + b0[1024 + k];
        float zo = sv * W0[1536 + k] + b0[1536 + k];
        float c0 = sigf(zi) * tanh_fast(zg);
        po[jj] = sigf(zo) * tanh_fast(c0);
    }
    *(float4*)(h0T + (size_t)s * D_ + kq) = o;
}

__global__ __launch_bounds__(256) void k_gates1(
    const float* __restrict__ z1T, const float* __restrict__ b1,
    float* __restrict__ h1c1T) {
    int idx4 = blockIdx.x * 256 + threadIdx.x;
    int s = idx4 >> 7, dq = (idx4 & 127) * 4;
    const float* z = z1T + (size_t)s * G_;
    float4 hv, cv;
    float* ph = &hv.x; float* pc = &cv.x;
    #pragma unroll
    for (int jj = 0; jj < 4; ++jj) {
        int d = dq + jj;
        float zi = z[d] + b1[d];
        float zg = z[1024 + d] + b1[1024 + d];
        float zo = z[1536 + d] + b1[1536 + d];
        float c1 = sigf(zi) * tanh_fast(zg);
        pc[jj] = c1;
        ph[jj] = sigf(zo) * tanh_fast(c1);
    }
    *(float4*)(h1c1T + (size_t)s * (2 * D_) + dq) = hv;
    *(float4*)(h1c1T + (size_t)s * (2 * D_) + D_ + dq) = cv;
}

__global__ __launch_bounds__(256) void k_xd(
    const float* __restrict__ inp, const float* __restrict__ Wd,
    const float* __restrict__ bd, float* __restrict__ xd) {
    int id = blockIdx.x * 256 + threadIdx.x;
    const float* row = inp + (size_t)id * F_;
    float s = 0.f;
    #pragma unroll
    for (int f = 0; f < F_; ++f) s += row[f] * Wd[f];
    xd[id] = s + bd[0];
}

// f32 -> bf16 (RNE), 8 elems/thread
__global__ __launch_bounds__(256) void k_cvt_bf16(
    const float* __restrict__ src, unsigned short* __restrict__ dst) {
    size_t i = ((size_t)blockIdx.x * 256 + threadIdx.x) * 8;
    float4 a = *(const float4*)(src + i);
    float4 b = *(const float4*)(src + i + 4);
    float v[8] = {a.x, a.y, a.z, a.w, b.x, b.y, b.z, b.w};
    unsigned int pk[4];
    #pragma unroll
    for (int j = 0; j < 4; ++j) {
        unsigned int u0 = __float_as_uint(v[2 * j]);
        unsigned int u1 = __float_as_uint(v[2 * j + 1]);
        u0 = (u0 + 0x7fffu + ((u0 >> 16) & 1u)) >> 16;
        u1 = (u1 + 0x7fffu + ((u1 >> 16) & 1u)) >> 16;
        pk[j] = u0 | (u1 << 16);
    }
    *(uint4*)(dst + i) = make_uint4(pk[0], pk[1], pk[2], pk[3]);
}

// e2[row] = enc[row,:] . Wd2   (row = b*T + t'), wave per row
__global__ __launch_bounds__(256) void k_e2(
    const float* __restrict__ enc, const float* __restrict__ Wd2,
    float* __restrict__ e2) {
    const int row = blockIdx.x * 4 + (threadIdx.x >> 6);
    const int lane = threadIdx.x & 63;
    const float* p = enc + (size_t)row * U_ + lane * 8;
    float4 a = *(const float4*)p;
    float4 c = *(const float4*)(p + 4);
    const float* w = Wd2 + lane * 8;
    float4 wa = *(const float4*)w;
    float4 wc = *(const float4*)(w + 4);
    float s = a.x*wa.x + a.y*wa.y + a.z*wa.z + a.w*wa.w
            + c.x*wc.x + c.y*wc.y + c.z*wc.z + c.w*wc.w;
    #pragma unroll
    for (int off = 32; off; off >>= 1) s += __shfl_xor(s, off);
    if (lane == 0) e2[row] = s;
}

// ---------------------------------------------------------------------------
// Score table: s_tab[b][t'][k] = sum_a tanh(qT[16k][a] + ep[b,t'][a]) * v[a].
// grid B*64 blocks (t'-pairs), 256 threads: thread -> (k = tid>>1, half = tid&1).
__global__ __launch_bounds__(256) void k_stab(
    const float* __restrict__ qT, const unsigned short* __restrict__ ep_bf,
    const float* __restrict__ v_att, float* __restrict__ s_tab) {
    const int b = blockIdx.x >> 6;
    const int tpr = (blockIdx.x & 63) * 2;
    const int tid = threadIdx.x;
    __shared__ float epL[2][512];
    __shared__ float vL[512];
    {
        int row = tid >> 7, a4 = (tid & 127) * 4;
        const unsigned short* src = ep_bf + ((size_t)b * T_ + tpr + row) * A_ + a4;
        uint2 rv = *(const uint2*)src;
        epL[row][a4 + 0] = bflo(rv.x); epL[row][a4 + 1] = bfhi(rv.x);
        epL[row][a4 + 2] = bflo(rv.y); epL[row][a4 + 3] = bfhi(rv.y);
        vL[tid] = v_att[tid];
        vL[tid + 256] = v_att[tid + 256];
    }
    __syncthreads();
    const int k = tid >> 1, half = tid & 1;
    const float* qrow = qT + (size_t)(k * 16) * A_ + half * 256;
    const float* e0p = &epL[0][half * 256];
    const float* e1p = &epL[1][half * 256];
    const float* vp  = &vL[half * 256];
    float s0 = 0.f, s1 = 0.f;
    #pragma unroll 4
    for (int a = 0; a < 256; ++a) {
        float q = qrow[a], v = vp[a];
        s0 += tanh_fast(q + e0p[a]) * v;
        s1 += tanh_fast(q + e1p[a]) * v;
    }
    s0 += __shfl_xor(s0, 1);
    s1 += __shfl_xor(s1, 1);
    if (half == 0) {
        s_tab[((size_t)b * T_ + tpr) * KS_ + k] = s0;
        s_tab[((size_t)b * T_ + tpr + 1) * KS_ + k] = s1;
    }
}

// ---------------------------------------------------------------------------
// Full xin recurrence, one kernel. 256 independent blocks (one per b), 1 wave.
// Lane owns t' = {lane, lane+64}; shuffle-only softmax + e2 dot.
__global__ __launch_bounds__(64) void k_chain(
    const float* __restrict__ s_tab, const float* __restrict__ e2,
    const float* __restrict__ xd, float* __restrict__ xinA) {
    const int b = blockIdx.x;
    const int lane = threadIdx.x;
    const float e20 = e2[b * T_ + lane];
    const float e21 = e2[b * T_ + lane + 64];
    const float* st0 = s_tab + ((size_t)b * T_ + lane) * KS_;
    const float* st1 = s_tab + ((size_t)b * T_ + lane + 64) * KS_;
    float xin = xd[b * T_];
    for (int t = 0; t < T_; ++t) {
        if (lane == 0) xinA[t * B_ + b] = xin;
        float u = (xin - LOS_) * IDTS_;
        u = fminf(fmaxf(u, 0.0f), (float)KS_ - 1.001f);
        int k0 = (int)u; float fr = u - (float)k0;
        float a0 = st0[k0], a1 = st0[k0 + 1];
        float c0 = st1[k0], c1 = st1[k0 + 1];
        float s0 = a0 + fr * (a1 - a0);
        float s1 = c0 + fr * (c1 - c0);
        float m = fmaxf(s0, s1);
        #pragma unroll
        for (int off = 32; off; off >>= 1) m = fmaxf(m, __shfl_xor(m, off));
        float ex0 = __expf(s0 - m), ex1 = __expf(s1 - m);
        float num = ex0 * e20 + ex1 * e21;
        float den = ex0 + ex1;
        #pragma unroll
        for (int off = 32; off; off >>= 1) {
            num += __shfl_xor(num, off);
            den += __shfl_xor(den, off);
        }
        if (t + 1 < T_) xin = xd[b * T_ + t + 1] + num / den;
    }
}

// ---------------------------------------------------------------------------
// All contexts at once. grid (B*8): b = bid>>3, t-group of 16. 512 threads.
__global__ __launch_bounds__(512) void k_ctx_all(
    const float* __restrict__ qT, const float* __restrict__ xinA,
    const float* __restrict__ v_att,
    const unsigned short* __restrict__ ep_bf,
    const unsigned short* __restrict__ enc_bf,
    float* __restrict__ ctx_all) {
    const int b = blockIdx.x >> 3;
    const int t0 = (blockIdx.x & 7) * 16;
    const int tid = threadIdx.x;
    const int wave = tid >> 6, lane = tid & 63;
    __shared__ float qL[16][512];
    __shared__ float sL[16][128];
    __shared__ float cp[512];
    // stage interpolated q rows
    #pragma unroll 4
    for (int r = 0; r < 16; ++r) {
        float xin = xinA[(t0 + r) * B_ + b];
        float u = (xin - LO_) * IDT_;
        u = fminf(fmaxf(u, 0.0f), (float)NS_ - 1.001f);
        int i0 = (int)u; float fr = u - (float)i0;
        float lo = qT[(size_t)i0 * A_ + tid];
        float hi = qT[(size_t)(i0 + 1) * A_ + tid];
        qL[r][tid] = lo + fr * (hi - lo);
    }
    __syncthreads();
    // phase A: exact scores; wave w handles rows 2w, 2w+1
    {
        const int r0 = wave * 2, r1 = r0 + 1;
        float q0[8], q1[8], v8[8];
        #pragma unroll
        for (int j = 0; j < 8; ++j) {
            q0[j] = qL[r0][lane * 8 + j];
            q1[j] = qL[r1][lane * 8 + j];
            v8[j] = v_att[lane * 8 + j];
        }
        for (int tp = 0; tp < T_; ++tp) {
            const unsigned short* row = ep_bf + ((size_t)b * T_ + tp) * A_ + lane * 8;
            uint4 rv = *(const uint4*)row;
            unsigned int uw[4] = {rv.x, rv.y, rv.z, rv.w};
            float s0 = 0.f, s1 = 0.f;
            #pragma unroll
            for (int j = 0; j < 4; ++j) {
                float e0 = bflo(uw[j]), e1 = bfhi(uw[j]);
                s0 += tanh_fast(q0[2 * j]     + e0) * v8[2 * j];
                s0 += tanh_fast(q0[2 * j + 1] + e1) * v8[2 * j + 1];
                s1 += tanh_fast(q1[2 * j]     + e0) * v8[2 * j];
                s1 += tanh_fast(q1[2 * j + 1] + e1) * v8[2 * j + 1];
            }
            #pragma unroll
            for (int off = 32; off; off >>= 1) {
                s0 += __shfl_xor(s0, off);
                s1 += __shfl_xor(s1, off);
            }
            if (lane == 0) { sL[r0][tp] = s0; sL[r1][tp] = s1; }
        }
    }
    __syncthreads();
    // phase B: softmax per row; 32 lanes per row (aligned), 4 entries/lane
    {
        const int r = tid >> 5, s4 = (tid & 31) * 4;
        float4 sv = *(const float4*)&sL[r][s4];
        float m = fmaxf(fmaxf(sv.x, sv.y), fmaxf(sv.z, sv.w));
        #pragma unroll
        for (int off = 16; off; off >>= 1) m = fmaxf(m, __shfl_xor(m, off));
        float e0 = __expf(sv.x - m), e1 = __expf(sv.y - m);
        float e2v = __expf(sv.z - m), e3 = __expf(sv.w - m);
        float ss = e0 + e1 + e2v + e3;
        #pragma unroll
        for (int off = 16; off; off >>= 1) ss += __shfl_xor(ss, off);
        float inv = 1.0f / ss;
        sL[r][s4] = e0 * inv; sL[r][s4 + 1] = e1 * inv;
        sL[r][s4 + 2] = e2v * inv; sL[r][s4 + 3] = e3 * inv;
    }
    __syncthreads();
    // phase C: ctx[t0+r][b][u] = sum_tp w * enc; thread (u2, tp-half g)
    const int g = tid >> 8, u2 = (tid & 255) * 2;
    for (int r = 0; r < 16; ++r) {
        const float* wp = &sL[r][g * 64];
        const unsigned short* base = enc_bf + ((size_t)b * T_ + g * 64) * U_ + u2;
        float ax = 0.f, ay = 0.f;
        #pragma unroll 8
        for (int tp = 0; tp < 64; ++tp) {
            unsigned int w2 = *(const unsigned int*)(base + (size_t)tp * U_);
            float w = wp[tp];
            ax += w * bflo(w2);
            ay += w * bfhi(w2);
        }
        if (g == 1) { cp[u2] = ax; cp[u2 + 1] = ay; }
        __syncthreads();
        if (g == 0)
            *(float2*)(ctx_all + ((size_t)(t0 + r) * B_ + b) * U_ + u2) =
                make_float2(ax + cp[u2], ay + cp[u2 + 1]);
        __syncthreads();
    }
}

// ---------------------------------------------------------------------------
// Final LSTM split-source GEMM: zp[s][i][n], s=0: h_f@Uf; s=1: gathered-ctx@Wf2.
__global__ __launch_bounds__(256) void k_fstep(
    const float* __restrict__ h_f, const float* __restrict__ ctx_all,
    const float* __restrict__ Uf, const float* __restrict__ Wf2,
    float* __restrict__ zp, int j) {
    constexpr int BK = 16;
    __shared__ float As[BK][36];
    __shared__ float Bs[BK][64];
    const int s = blockIdx.z;
    const int n0 = blockIdx.x * 64, m0 = blockIdx.y * 32;
    const int tid = threadIdx.x, tx = tid & 15, ty = tid >> 4;
    const int am = tid >> 2, ak4 = (tid & 3) * 4;
    const float* arow = nullptr;
    if (tid < 128) {
        int i = m0 + am;
        if (s == 0) arow = h_f + (size_t)i * D_;
        else {
            int tt = i >> 1, bb = ((i & 1) << 7) + j;
            arow = ctx_all + ((size_t)tt * B_ + bb) * U_;
        }
    }
    const float* Bmat = (s == 0) ? Uf : Wf2;
    const int bk = tid >> 4, bn4 = (tid & 15) * 4;
    const float* bp = Bmat + (size_t)bk * G_ + n0 + bn4;
    float4 ar = (tid < 128) ? *(const float4*)(arow + ak4) : make_float4(0, 0, 0, 0);
    float4 br = *(const float4*)(bp);
    float acc[2][4] = {};
    for (int k0 = 0; k0 < 512; k0 += BK) {
        __syncthreads();
        if (tid < 128) {
            As[ak4 + 0][am] = ar.x; As[ak4 + 1][am] = ar.y;
            As[ak4 + 2][am] = ar.z; As[ak4 + 3][am] = ar.w;
        }
        *(float4*)&Bs[bk][bn4] = br;
        __syncthreads();
        if (k0 + BK < 512) {
            if (tid < 128) ar = *(const float4*)(arow + k0 + BK + ak4);
            br = *(const float4*)(bp + (size_t)(k0 + BK) * G_);
        }
        #pragma unroll
        for (int kk = 0; kk < BK; ++kk) {
            float2 a = *(const float2*)&As[kk][ty * 2];
            float4 b = *(const float4*)&Bs[kk][tx * 4];
            acc[0][0] += a.x * b.x; acc[0][1] += a.x * b.y; acc[0][2] += a.x * b.z; acc[0][3] += a.x * b.w;
            acc[1][0] += a.y * b.x; acc[1][1] += a.y * b.y; acc[1][2] += a.y * b.z; acc[1][3] += a.y * b.w;
        }
    }
    float* dst = zp + (size_t)s * (B_ * G_);
    #pragma unroll
    for (int im = 0; im < 2; ++im)
        *(float4*)(dst + (size_t)(m0 + ty * 2 + im) * G_ + n0 + tx * 4) =
            make_float4(acc[im][0], acc[im][1], acc[im][2], acc[im][3]);
}

// Final gates: z = zp0+zp1 + interp(zhT) + bf; update h_f,c_f; write out[i][j].
__global__ __launch_bounds__(256) void k_fgate(
    const float* __restrict__ zp, const float* __restrict__ zhT,
    const float* __restrict__ xinA, const float* __restrict__ bf,
    float* __restrict__ h_f, float* __restrict__ c_f,
    float* __restrict__ out, int j) {
    const int i = blockIdx.x, tid = threadIdx.x;
    const int tt = i >> 1, bb = ((i & 1) << 7) + j;
    float xin = xinA[tt * B_ + bb];
    float u = (xin - LO_) * IDT_;
    u = fminf(fmaxf(u, 0.0f), (float)NS_ - 1.001f);
    int i0 = (int)u; float fr = u - (float)i0;
    const float* zh0 = zhT + (size_t)i0 * G_;
    const float* zh1 = zh0 + G_;
    const float* z0 = zp + (size_t)i * G_;
    const float* z1 = zp + (size_t)(B_ + i) * G_;
    #pragma unroll
    for (int p = 0; p < 2; ++p) {
        int d = p * 256 + tid;
        float zg4[4];
        #pragma unroll
        for (int g = 0; g < 4; ++g) {
            int col = g * 512 + d;
            float lo = zh0[col];
            zg4[g] = z0[col] + z1[col] + lo + fr * (zh1[col] - lo) + bf[col];
        }
        float c_old = c_f[(size_t)i * D_ + d];
        float cn = sigf(zg4[1]) * c_old + sigf(zg4[0]) * tanh_fast(zg4[2]);
        float hn = sigf(zg4[3]) * tanh_fast(cn);
        c_f[(size_t)i * D_ + d] = cn;
        h_f[(size_t)i * D_ + d] = hn;
        out[((size_t)i * T_ + j) * D_ + d] = hn;
    }
}

// ---------------------------------------------------------------------------
extern "C" void kernel_launch(void* const* d_in, const int* in_sizes, int n_in,
                              void* d_out, int out_size, void* d_ws, size_t ws_size,
                              hipStream_t stream) {
    const float* inputs = (const float*)d_in[0];
    const float* enc    = (const float*)d_in[1];
    const float* Wd     = (const float*)d_in[2];
    const float* bd     = (const float*)d_in[3];
    const float* W0     = (const float*)d_in[4];
    const float* b0     = (const float*)d_in[6];
    const float* W1     = (const float*)d_in[7];
    const float* b1     = (const float*)d_in[9];
    const float* Wq     = (const float*)d_in[10];
    const float* Wk     = (const float*)d_in[11];
    const float* v_att  = (const float*)d_in[12];
    const float* Wf     = (const float*)d_in[13];
    const float* Uf     = (const float*)d_in[14];
    const float* bf     = (const float*)d_in[15];
    float* out = (float*)d_out;

    float* ws = (float*)d_ws;
    unsigned short* ep_bf  = (unsigned short*)ws;               //  8,388,608 f slots
    unsigned short* enc_bf = (unsigned short*)(ws + 8388608);   //  8,388,608 f
    float* ctx_all = ws + (size_t)16777216;                     // 16,777,216 f  [T][B][U]
    float* qT      = ctx_all + (size_t)16777216;                //  1,048,576 f
    float* zhT     = qT + (size_t)1048576;                      //  4,194,304 f
    float* h0T     = zhT + (size_t)4194304;                     //  1,048,576 f
    float* h1c1T   = h0T + (size_t)1048576;                     //  2,097,152 f
    float* s_tab   = h1c1T + (size_t)2097152;                   //  4,194,304 f [B][T][KS]
    float* e2      = s_tab + (size_t)4194304;                   //     32,768 f
    float* xd      = e2 + 32768;                                //     32,768 f
    float* xinA    = xd + 32768;                                //     32,768 f [T][B]
    float* zp      = xinA + 32768;                              //  1,048,576 f
    float* h_f     = zp + 1048576;                              //    131,072 f
    float* c_f     = h_f + 131072;                              //    131,072 f
    // aliases on ctx_all (consumed strictly before ctx_all is written):
    float* z1T    = ctx_all;   // NS x G table intermediate
    float* ep_tmp = ctx_all;   // f32 enc projection

    // ---- one-time tables
    k_h0build<<<dim3(NS_ * D_ / 1024), 256, 0, stream>>>(W0, b0, h0T);
    k_gemm128<<<dim3(G_ / 128, NS_ / 128), 256, 0, stream>>>(h0T, D_, W1, G_, z1T, G_, D_);
    k_gates1<<<dim3(NS_ * D_ / 1024), 256, 0, stream>>>(z1T, b1, h1c1T);
    k_gemm128<<<dim3(A_ / 128, NS_ / 128), 256, 0, stream>>>(h1c1T, 2 * D_, Wq, A_, qT, A_, 2 * D_);
    k_gemm128<<<dim3(G_ / 128, NS_ / 128), 256, 0, stream>>>(h1c1T, 2 * D_, Wf, G_, zhT, G_, D_);
    k_gemm128<<<dim3(A_ / 128, (B_ * T_) / 128), 256, 0, stream>>>(enc, U_, Wk, A_, ep_tmp, A_, U_);
    k_cvt_bf16<<<dim3(8192), 256, 0, stream>>>(ep_tmp, ep_bf);
    k_cvt_bf16<<<dim3(8192), 256, 0, stream>>>(enc, enc_bf);
    k_xd<<<dim3(B_ * T_ / 256), 256, 0, stream>>>(inputs, Wd, bd, xd);
    k_e2<<<dim3(B_ * T_ / 4), 256, 0, stream>>>(enc, Wd + F_, e2);

    hipMemsetAsync(h_f, 0, (size_t)B_ * D_ * sizeof(float), stream);
    hipMemsetAsync(c_f, 0, (size_t)B_ * D_ * sizeof(float), stream);

    // ---- decoder: score table -> scalar chain -> all contexts
    k_stab<<<dim3(B_ * 64), 256, 0, stream>>>(qT, ep_bf, v_att, s_tab);
    k_chain<<<dim3(B_), 64, 0, stream>>>(s_tab, e2, xd, xinA);
    k_ctx_all<<<dim3(B_ * 8), 512, 0, stream>>>(qT, xinA, v_att, ep_bf, enc_bf, ctx_all);

    // ---- final LSTM loop
    const float* Wf2 = Wf + (size_t)D_ * G_;
    for (int j = 0; j < T_; ++j) {
        k_fstep<<<dim3(G_ / 64, B_ / 32, 2), 256, 0, stream>>>(h_f, ctx_all, Uf, Wf2, zp, j);
        k_fgate<<<dim3(B_), 256, 0, stream>>>(zp, zhT, xinA, bf, h_f, c_f, out, j);
    }
}

// Round 6
// 4448.924 us; speedup vs baseline: 4.6755x; 1.4825x over previous
//
#include <hip/hip_runtime.h>

// Problem constants
constexpr int B_ = 256;
constexpr int T_ = 128;
constexpr int F_ = 32;
constexpr int U_ = 512;   // U_ENC
constexpr int D_ = 512;
constexpr int A_ = 512;
constexpr int G_ = 2048;  // 4*D

// xin lookup tables: qT/zhT grid (fine), s_tab grid (coarse)
constexpr int   NS_   = 2048;
constexpr float LO_   = -8.0f;
constexpr float IDT_  = 128.0f;   // spacing 1/128 over [-8,8)
constexpr int   KS_   = 128;
constexpr float LOS_  = -8.0f;
constexpr float IDTS_ = 8.0f;     // spacing 1/8; s-grid k <-> qT row 16k

typedef short bf16x8 __attribute__((ext_vector_type(8)));
typedef float f32x4 __attribute__((ext_vector_type(4)));

__device__ __forceinline__ float sigf(float x) { return 1.0f / (1.0f + __expf(-x)); }
__device__ __forceinline__ float tanh_fast(float x) {
    return 2.0f / (1.0f + __expf(-2.0f * x)) - 1.0f;
}
__device__ __forceinline__ float bflo(unsigned int u) { return __uint_as_float(u << 16); }
__device__ __forceinline__ float bfhi(unsigned int u) { return __uint_as_float(u & 0xffff0000u); }
__device__ __forceinline__ unsigned short f2bf(float x) {
    unsigned int u = __float_as_uint(x);
    u = (u + 0x7fffu + ((u >> 16) & 1u)) >> 16;
    return (unsigned short)u;
}

// ---------------------------------------------------------------------------
// Generic f32 GEMM: C[M,N] = A[M,K]@B[K,N].  BM=BN=128, BK=16, TM=TN=8.
__global__ __launch_bounds__(256) void k_gemm128(
    const float* __restrict__ A, int lda,
    const float* __restrict__ Bm, int ldb,
    float* __restrict__ C, int ldc, int K) {
    constexpr int BK = 16;
    __shared__ float As[BK][132];
    __shared__ float Bs[BK][128];
    const int tid = threadIdx.x;
    const int tx = tid & 15, ty = tid >> 4;
    const int m0 = blockIdx.y * 128, n0 = blockIdx.x * 128;
    const int am0 = tid >> 2,          ak40 = (tid & 3) * 4;
    const int am1 = (256 + tid) >> 2,  ak41 = ((256 + tid) & 3) * 4;
    const int bk0 = tid >> 5,          bn40 = (tid & 31) * 4;
    const int bk1 = (256 + tid) >> 5,  bn41 = ((256 + tid) & 31) * 4;
    const float* a0p = A + (size_t)(m0 + am0) * lda + ak40;
    const float* a1p = A + (size_t)(m0 + am1) * lda + ak41;
    const float* b0p = Bm + (size_t)bk0 * ldb + n0 + bn40;
    const float* b1p = Bm + (size_t)bk1 * ldb + n0 + bn41;
    float4 ar0 = *(const float4*)(a0p);
    float4 ar1 = *(const float4*)(a1p);
    float4 br0 = *(const float4*)(b0p);
    float4 br1 = *(const float4*)(b1p);
    float acc[8][8] = {};
    for (int k0 = 0; k0 < K; k0 += BK) {
        __syncthreads();
        As[ak40 + 0][am0] = ar0.x; As[ak40 + 1][am0] = ar0.y;
        As[ak40 + 2][am0] = ar0.z; As[ak40 + 3][am0] = ar0.w;
        As[ak41 + 0][am1] = ar1.x; As[ak41 + 1][am1] = ar1.y;
        As[ak41 + 2][am1] = ar1.z; As[ak41 + 3][am1] = ar1.w;
        *(float4*)&Bs[bk0][bn40] = br0;
        *(float4*)&Bs[bk1][bn41] = br1;
        __syncthreads();
        if (k0 + BK < K) {
            ar0 = *(const float4*)(a0p + k0 + BK);
            ar1 = *(const float4*)(a1p + k0 + BK);
            br0 = *(const float4*)(b0p + (size_t)(k0 + BK) * ldb);
            br1 = *(const float4*)(b1p + (size_t)(k0 + BK) * ldb);
        }
        #pragma unroll
        for (int kk = 0; kk < BK; ++kk) {
            float a[8], b[8];
            *(float4*)&a[0] = *(const float4*)&As[kk][ty * 8];
            *(float4*)&a[4] = *(const float4*)&As[kk][ty * 8 + 4];
            *(float4*)&b[0] = *(const float4*)&Bs[kk][tx * 8];
            *(float4*)&b[4] = *(const float4*)&Bs[kk][tx * 8 + 4];
            #pragma unroll
            for (int im = 0; im < 8; ++im)
                #pragma unroll
                for (int in = 0; in < 8; ++in)
                    acc[im][in] += a[im] * b[in];
        }
    }
    #pragma unroll
    for (int im = 0; im < 8; ++im) {
        float* crow = C + (size_t)(m0 + ty * 8 + im) * ldc + n0 + tx * 8;
        *(float4*)(crow)     = make_float4(acc[im][0], acc[im][1], acc[im][2], acc[im][3]);
        *(float4*)(crow + 4) = make_float4(acc[im][4], acc[im][5], acc[im][6], acc[im][7]);
    }
}

// ---------------------------------------------------------------------------
__global__ __launch_bounds__(256) void k_h0build(
    const float* __restrict__ W0, const float* __restrict__ b0,
    float* __restrict__ h0T) {
    int idx4 = blockIdx.x * 256 + threadIdx.x;
    int s = idx4 >> 7, kq = (idx4 & 127) * 4;
    float sv = LO_ + (float)s * (1.0f / IDT_);
    float4 o;
    float* po = &o.x;
    #pragma unroll
    for (int jj = 0; jj < 4; ++jj) {
        int k = kq + jj;
        float zi = sv * W0[k] + b0[k];
        float zg = sv * W0[1024 + k] + b0[1024 + k];
        float zo = sv * W0[1536 + k] + b0[1536 + k];
        float c0 = sigf(zi) * tanh_fast(zg);
        po[jj] = sigf(zo) * tanh_fast(c0);
    }
    *(float4*)(h0T + (size_t)s * D_ + kq) = o;
}

__global__ __launch_bounds__(256) void k_gates1(
    const float* __restrict__ z1T, const float* __restrict__ b1,
    float* __restrict__ h1c1T) {
    int idx4 = blockIdx.x * 256 + threadIdx.x;
    int s = idx4 >> 7, dq = (idx4 & 127) * 4;
    const float* z = z1T + (size_t)s * G_;
    float4 hv, cv;
    float* ph = &hv.x; float* pc = &cv.x;
    #pragma unroll
    for (int jj = 0; jj < 4; ++jj) {
        int d = dq + jj;
        float zi = z[d] + b1[d];
        float zg = z[1024 + d] + b1[1024 + d];
        float zo = z[1536 + d] + b1[1536 + d];
        float c1 = sigf(zi) * tanh_fast(zg);
        pc[jj] = c1;
        ph[jj] = sigf(zo) * tanh_fast(c1);
    }
    *(float4*)(h1c1T + (size_t)s * (2 * D_) + dq) = hv;
    *(float4*)(h1c1T + (size_t)s * (2 * D_) + D_ + dq) = cv;
}

__global__ __launch_bounds__(256) void k_xd(
    const float* __restrict__ inp, const float* __restrict__ Wd,
    const float* __restrict__ bd, float* __restrict__ xd) {
    int id = blockIdx.x * 256 + threadIdx.x;
    const float* row = inp + (size_t)id * F_;
    float s = 0.f;
    #pragma unroll
    for (int f = 0; f < F_; ++f) s += row[f] * Wd[f];
    xd[id] = s + bd[0];
}

// f32 -> bf16 (RNE), 8 elems/thread
__global__ __launch_bounds__(256) void k_cvt_bf16(
    const float* __restrict__ src, unsigned short* __restrict__ dst) {
    size_t i = ((size_t)blockIdx.x * 256 + threadIdx.x) * 8;
    float4 a = *(const float4*)(src + i);
    float4 b = *(const float4*)(src + i + 4);
    float v[8] = {a.x, a.y, a.z, a.w, b.x, b.y, b.z, b.w};
    unsigned int pk[4];
    #pragma unroll
    for (int j = 0; j < 4; ++j) {
        unsigned int u0 = (unsigned int)f2bf(v[2 * j]);
        unsigned int u1 = (unsigned int)f2bf(v[2 * j + 1]);
        pk[j] = u0 | (u1 << 16);
    }
    *(uint4*)(dst + i) = make_uint4(pk[0], pk[1], pk[2], pk[3]);
}

// e2[row] = enc[row,:] . Wd2   (row = b*T + t'), wave per row
__global__ __launch_bounds__(256) void k_e2(
    const float* __restrict__ enc, const float* __restrict__ Wd2,
    float* __restrict__ e2) {
    const int row = blockIdx.x * 4 + (threadIdx.x >> 6);
    const int lane = threadIdx.x & 63;
    const float* p = enc + (size_t)row * U_ + lane * 8;
    float4 a = *(const float4*)p;
    float4 c = *(const float4*)(p + 4);
    const float* w = Wd2 + lane * 8;
    float4 wa = *(const float4*)w;
    float4 wc = *(const float4*)(w + 4);
    float s = a.x*wa.x + a.y*wa.y + a.z*wa.z + a.w*wa.w
            + c.x*wc.x + c.y*wc.y + c.z*wc.z + c.w*wc.w;
    #pragma unroll
    for (int off = 32; off; off >>= 1) s += __shfl_xor(s, off);
    if (lane == 0) e2[row] = s;
}

// ---------------------------------------------------------------------------
// Score table: s_tab[b][t'][k] = sum_a tanh(qT[16k][a] + ep[b,t'][a]) * v[a].
__global__ __launch_bounds__(256) void k_stab(
    const float* __restrict__ qT, const unsigned short* __restrict__ ep_bf,
    const float* __restrict__ v_att, float* __restrict__ s_tab) {
    const int b = blockIdx.x >> 6;
    const int tpr = (blockIdx.x & 63) * 2;
    const int tid = threadIdx.x;
    __shared__ float epL[2][512];
    __shared__ float vL[512];
    {
        int row = tid >> 7, a4 = (tid & 127) * 4;
        const unsigned short* src = ep_bf + ((size_t)b * T_ + tpr + row) * A_ + a4;
        uint2 rv = *(const uint2*)src;
        epL[row][a4 + 0] = bflo(rv.x); epL[row][a4 + 1] = bfhi(rv.x);
        epL[row][a4 + 2] = bflo(rv.y); epL[row][a4 + 3] = bfhi(rv.y);
        vL[tid] = v_att[tid];
        vL[tid + 256] = v_att[tid + 256];
    }
    __syncthreads();
    const int k = tid >> 1, half = tid & 1;
    const float* qrow = qT + (size_t)(k * 16) * A_ + half * 256;
    const float* e0p = &epL[0][half * 256];
    const float* e1p = &epL[1][half * 256];
    const float* vp  = &vL[half * 256];
    float s0 = 0.f, s1 = 0.f;
    #pragma unroll 4
    for (int a = 0; a < 256; ++a) {
        float q = qrow[a], v = vp[a];
        s0 += tanh_fast(q + e0p[a]) * v;
        s1 += tanh_fast(q + e1p[a]) * v;
    }
    s0 += __shfl_xor(s0, 1);
    s1 += __shfl_xor(s1, 1);
    if (half == 0) {
        s_tab[((size_t)b * T_ + tpr) * KS_ + k] = s0;
        s_tab[((size_t)b * T_ + tpr + 1) * KS_ + k] = s1;
    }
}

// ---------------------------------------------------------------------------
// Full xin recurrence, one kernel. 256 blocks (one per b), 1 wave each.
__global__ __launch_bounds__(64) void k_chain(
    const float* __restrict__ s_tab, const float* __restrict__ e2,
    const float* __restrict__ xd, float* __restrict__ xinA) {
    const int b = blockIdx.x;
    const int lane = threadIdx.x;
    const float e20 = e2[b * T_ + lane];
    const float e21 = e2[b * T_ + lane + 64];
    const float* st0 = s_tab + ((size_t)b * T_ + lane) * KS_;
    const float* st1 = s_tab + ((size_t)b * T_ + lane + 64) * KS_;
    float xin = xd[b * T_];
    for (int t = 0; t < T_; ++t) {
        if (lane == 0) xinA[t * B_ + b] = xin;
        float u = (xin - LOS_) * IDTS_;
        u = fminf(fmaxf(u, 0.0f), (float)KS_ - 1.001f);
        int k0 = (int)u; float fr = u - (float)k0;
        float a0 = st0[k0], a1 = st0[k0 + 1];
        float c0 = st1[k0], c1 = st1[k0 + 1];
        float s0 = a0 + fr * (a1 - a0);
        float s1 = c0 + fr * (c1 - c0);
        float m = fmaxf(s0, s1);
        #pragma unroll
        for (int off = 32; off; off >>= 1) m = fmaxf(m, __shfl_xor(m, off));
        float ex0 = __expf(s0 - m), ex1 = __expf(s1 - m);
        float num = ex0 * e20 + ex1 * e21;
        float den = ex0 + ex1;
        #pragma unroll
        for (int off = 32; off; off >>= 1) {
            num += __shfl_xor(num, off);
            den += __shfl_xor(den, off);
        }
        if (t + 1 < T_) xin = xd[b * T_ + t + 1] + num / den;
    }
}

// ---------------------------------------------------------------------------
// All contexts at once. grid (B*8): b = bid>>3, t-group of 16. 512 threads.
__global__ __launch_bounds__(512) void k_ctx_all(
    const float* __restrict__ qT, const float* __restrict__ xinA,
    const float* __restrict__ v_att,
    const unsigned short* __restrict__ ep_bf,
    const unsigned short* __restrict__ enc_bf,
    float* __restrict__ ctx_all) {
    const int b = blockIdx.x >> 3;
    const int t0 = (blockIdx.x & 7) * 16;
    const int tid = threadIdx.x;
    const int wave = tid >> 6, lane = tid & 63;
    __shared__ float qL[16][512];
    __shared__ float sL[16][128];
    __shared__ float cp[512];
    #pragma unroll 4
    for (int r = 0; r < 16; ++r) {
        float xin = xinA[(t0 + r) * B_ + b];
        float u = (xin - LO_) * IDT_;
        u = fminf(fmaxf(u, 0.0f), (float)NS_ - 1.001f);
        int i0 = (int)u; float fr = u - (float)i0;
        float lo = qT[(size_t)i0 * A_ + tid];
        float hi = qT[(size_t)(i0 + 1) * A_ + tid];
        qL[r][tid] = lo + fr * (hi - lo);
    }
    __syncthreads();
    {
        const int r0 = wave * 2, r1 = r0 + 1;
        float q0[8], q1[8], v8[8];
        #pragma unroll
        for (int j = 0; j < 8; ++j) {
            q0[j] = qL[r0][lane * 8 + j];
            q1[j] = qL[r1][lane * 8 + j];
            v8[j] = v_att[lane * 8 + j];
        }
        for (int tp = 0; tp < T_; ++tp) {
            const unsigned short* row = ep_bf + ((size_t)b * T_ + tp) * A_ + lane * 8;
            uint4 rv = *(const uint4*)row;
            unsigned int uw[4] = {rv.x, rv.y, rv.z, rv.w};
            float s0 = 0.f, s1 = 0.f;
            #pragma unroll
            for (int j = 0; j < 4; ++j) {
                float e0 = bflo(uw[j]), e1 = bfhi(uw[j]);
                s0 += tanh_fast(q0[2 * j]     + e0) * v8[2 * j];
                s0 += tanh_fast(q0[2 * j + 1] + e1) * v8[2 * j + 1];
                s1 += tanh_fast(q1[2 * j]     + e0) * v8[2 * j];
                s1 += tanh_fast(q1[2 * j + 1] + e1) * v8[2 * j + 1];
            }
            #pragma unroll
            for (int off = 32; off; off >>= 1) {
                s0 += __shfl_xor(s0, off);
                s1 += __shfl_xor(s1, off);
            }
            if (lane == 0) { sL[r0][tp] = s0; sL[r1][tp] = s1; }
        }
    }
    __syncthreads();
    {
        const int r = tid >> 5, s4 = (tid & 31) * 4;
        float4 sv = *(const float4*)&sL[r][s4];
        float m = fmaxf(fmaxf(sv.x, sv.y), fmaxf(sv.z, sv.w));
        #pragma unroll
        for (int off = 16; off; off >>= 1) m = fmaxf(m, __shfl_xor(m, off));
        float e0 = __expf(sv.x - m), e1 = __expf(sv.y - m);
        float e2v = __expf(sv.z - m), e3 = __expf(sv.w - m);
        float ss = e0 + e1 + e2v + e3;
        #pragma unroll
        for (int off = 16; off; off >>= 1) ss += __shfl_xor(ss, off);
        float inv = 1.0f / ss;
        sL[r][s4] = e0 * inv; sL[r][s4 + 1] = e1 * inv;
        sL[r][s4 + 2] = e2v * inv; sL[r][s4 + 3] = e3 * inv;
    }
    __syncthreads();
    const int g = tid >> 8, u2 = (tid & 255) * 2;
    for (int r = 0; r < 16; ++r) {
        const float* wp = &sL[r][g * 64];
        const unsigned short* base = enc_bf + ((size_t)b * T_ + g * 64) * U_ + u2;
        float ax = 0.f, ay = 0.f;
        #pragma unroll 8
        for (int tp = 0; tp < 64; ++tp) {
            unsigned int w2 = *(const unsigned int*)(base + (size_t)tp * U_);
            float w = wp[tp];
            ax += w * bflo(w2);
            ay += w * bfhi(w2);
        }
        if (g == 1) { cp[u2] = ax; cp[u2 + 1] = ay; }
        __syncthreads();
        if (g == 0)
            *(float2*)(ctx_all + ((size_t)(t0 + r) * B_ + b) * U_ + u2) =
                make_float2(ax + cp[u2], ay + cp[u2 + 1]);
        __syncthreads();
    }
}

// ---------------------------------------------------------------------------
// Build Wt[2048 cols][1024 k] bf16: Wt[c][k] = (k<512 ? Uf[k][c] : Wf[k][c]).
// grid (2048/64, 1024/64) = (32,16), 256 threads, LDS-transposed tiles.
__global__ __launch_bounds__(256) void k_wt(
    const float* __restrict__ Uf, const float* __restrict__ Wf,
    unsigned short* __restrict__ Wt) {
    __shared__ unsigned short tile[64][72];
    const int c0 = blockIdx.x * 64, k0 = blockIdx.y * 64;
    const int tid = threadIdx.x;
    const float* src = (k0 < 512) ? Uf : Wf;
    #pragma unroll
    for (int p = 0; p < 4; ++p) {
        int kk = (tid >> 4) + p * 16;
        int cc4 = (tid & 15) * 4;
        float4 v = *(const float4*)(src + (size_t)(k0 + kk) * G_ + c0 + cc4);
        tile[cc4 + 0][kk] = f2bf(v.x);
        tile[cc4 + 1][kk] = f2bf(v.y);
        tile[cc4 + 2][kk] = f2bf(v.z);
        tile[cc4 + 3][kk] = f2bf(v.w);
    }
    __syncthreads();
    #pragma unroll
    for (int p = 0; p < 4; ++p) {
        int cc = (tid >> 4) + p * 16;
        int k4 = (tid & 15) * 4;
        uint2 v = *(const uint2*)&tile[cc][k4];
        *(uint2*)(Wt + (size_t)(c0 + cc) * 1024 + k0 + k4) = v;
    }
}

// ---------------------------------------------------------------------------
// Final LSTM step, fully fused, MFMA. Grid (32 cg, 8 rg), 256 threads (4 waves).
// Block: 32 rows x (16 d-values x 4 gates = 64 z-cols), K=1024 ([h | ctx] bf16).
// Epilogue: + zhT interp + bf -> gates -> c_f, h(bf16, dbuf), out(f32).
__global__ __launch_bounds__(256) void k_frec(
    const unsigned short* __restrict__ hin, unsigned short* __restrict__ hout,
    const unsigned short* __restrict__ ctx_bf, const unsigned short* __restrict__ Wt,
    const float* __restrict__ zhT, const float* __restrict__ xinA,
    const float* __restrict__ bfv, float* __restrict__ c_f,
    float* __restrict__ out, int j) {
    __shared__ unsigned short As[32 * 72];
    __shared__ unsigned short Bs[64 * 72];
    __shared__ float zs[32 * 68];
    const int tid = threadIdx.x;
    const int lane = tid & 63, wave = tid >> 6;
    const int wr = wave >> 1, wc = wave & 1;
    const int d0 = blockIdx.x * 16;
    const int r0 = blockIdx.y * 32;
    // ---- staging coords
    const int ar_ = tid >> 3, aseg = tid & 7;
    const int ai = r0 + ar_;
    const size_t a_lo = (size_t)ai * 512 + aseg * 8;
    const size_t a_hi = ((size_t)(ai >> 1) * B_ + ((ai & 1) << 7) + j) * 512 + aseg * 8;
    const int bcA = tid >> 3, bcB = 32 + (tid >> 3), bseg = tid & 7;
    const size_t boffA = (size_t)(((bcA >> 4) << 9) + d0 + (bcA & 15)) * 1024 + bseg * 8;
    const size_t boffB = (size_t)(((bcB >> 4) << 9) + d0 + (bcB & 15)) * 1024 + bseg * 8;
    // ---- prefetch chunk 0
    uint4 av = *(const uint4*)(hin + a_lo);
    uint4 bv0 = *(const uint4*)(Wt + boffA);
    uint4 bv1 = *(const uint4*)(Wt + boffB);
    f32x4 acc0 = {0.f, 0.f, 0.f, 0.f};
    f32x4 acc1 = {0.f, 0.f, 0.f, 0.f};
    const int arow = 16 * wr + (lane & 15);
    const int brow0 = 32 * wc + (lane & 15);
    const int brow1 = brow0 + 16;
    const int koct = (lane >> 4) * 8;
    for (int kc = 0; kc < 16; ++kc) {
        __syncthreads();
        *(uint4*)&As[ar_ * 72 + aseg * 8] = av;
        *(uint4*)&Bs[bcA * 72 + bseg * 8] = bv0;
        *(uint4*)&Bs[bcB * 72 + bseg * 8] = bv1;
        __syncthreads();
        if (kc < 15) {
            const int k0 = (kc + 1) * 64;
            av = (k0 < 512) ? *(const uint4*)(hin + a_lo + k0)
                            : *(const uint4*)(ctx_bf + a_hi + (k0 - 512));
            bv0 = *(const uint4*)(Wt + boffA + k0);
            bv1 = *(const uint4*)(Wt + boffB + k0);
        }
        #pragma unroll
        for (int ks = 0; ks < 2; ++ks) {
            const int kb = ks * 32 + koct;
            bf16x8 af = *(const bf16x8*)&As[arow * 72 + kb];
            bf16x8 b0 = *(const bf16x8*)&Bs[brow0 * 72 + kb];
            bf16x8 b1 = *(const bf16x8*)&Bs[brow1 * 72 + kb];
            acc0 = __builtin_amdgcn_mfma_f32_16x16x32_bf16(af, b0, acc0, 0, 0, 0);
            acc1 = __builtin_amdgcn_mfma_f32_16x16x32_bf16(af, b1, acc1, 0, 0, 0);
        }
    }
    // ---- spill z to LDS (C/D layout: col=lane&15, row=(lane>>4)*4+reg)
    {
        const int srow = 16 * wr + (lane >> 4) * 4;
        const int scol = 32 * wc + (lane & 15);
        #pragma unroll
        for (int reg = 0; reg < 4; ++reg) {
            zs[(srow + reg) * 68 + scol] = acc0[reg];
            zs[(srow + reg) * 68 + scol + 16] = acc1[reg];
        }
    }
    __syncthreads();
    // ---- fused gate epilogue: 512 (row, d) items, 2 per thread
    #pragma unroll
    for (int p = 0; p < 2; ++p) {
        const int it = p * 256 + tid;
        const int r = it >> 4, dd = it & 15;
        const int i = r0 + r, d = d0 + dd;
        float zg4[4];
        zg4[0] = zs[r * 68 + dd];
        zg4[1] = zs[r * 68 + 16 + dd];
        zg4[2] = zs[r * 68 + 32 + dd];
        zg4[3] = zs[r * 68 + 48 + dd];
        const float xv = xinA[(i >> 1) * B_ + ((i & 1) << 7) + j];
        float u = (xv - LO_) * IDT_;
        u = fminf(fmaxf(u, 0.0f), (float)NS_ - 1.001f);
        const int i0 = (int)u;
        const float fr = u - (float)i0;
        const float* zh0 = zhT + (size_t)i0 * G_;
        const float* zh1 = zh0 + G_;
        #pragma unroll
        for (int g = 0; g < 4; ++g) {
            const int col = g * 512 + d;
            const float lo = zh0[col];
            zg4[g] += lo + fr * (zh1[col] - lo) + bfv[col];
        }
        const float co = c_f[(size_t)i * D_ + d];
        const float cn = sigf(zg4[1]) * co + sigf(zg4[0]) * tanh_fast(zg4[2]);
        const float hn = sigf(zg4[3]) * tanh_fast(cn);
        c_f[(size_t)i * D_ + d] = cn;
        hout[(size_t)i * D_ + d] = f2bf(hn);
        out[((size_t)i * T_ + j) * D_ + d] = hn;
    }
}

// ---------------------------------------------------------------------------
extern "C" void kernel_launch(void* const* d_in, const int* in_sizes, int n_in,
                              void* d_out, int out_size, void* d_ws, size_t ws_size,
                              hipStream_t stream) {
    const float* inputs = (const float*)d_in[0];
    const float* enc    = (const float*)d_in[1];
    const float* Wd     = (const float*)d_in[2];
    const float* bd     = (const float*)d_in[3];
    const float* W0     = (const float*)d_in[4];
    const float* b0     = (const float*)d_in[6];
    const float* W1     = (const float*)d_in[7];
    const float* b1     = (const float*)d_in[9];
    const float* Wq     = (const float*)d_in[10];
    const float* Wk     = (const float*)d_in[11];
    const float* v_att  = (const float*)d_in[12];
    const float* Wf     = (const float*)d_in[13];
    const float* Uf     = (const float*)d_in[14];
    const float* bf     = (const float*)d_in[15];
    float* out = (float*)d_out;

    float* ws = (float*)d_ws;
    unsigned short* ep_bf  = (unsigned short*)ws;               //  8,388,608 f-slots
    unsigned short* enc_bf = (unsigned short*)(ws + 8388608);   //  8,388,608
    float* ctx_all = ws + (size_t)16777216;                     // 16,777,216  [T][B][U]
    float* qT      = ctx_all + (size_t)16777216;                //  1,048,576
    float* zhT     = qT + (size_t)1048576;                      //  4,194,304
    float* h0T     = zhT + (size_t)4194304;                     //  1,048,576
    float* h1c1T   = h0T + (size_t)1048576;                     //  2,097,152
    float* s_tab   = h1c1T + (size_t)2097152;                   //  4,194,304
    float* e2      = s_tab + (size_t)4194304;                   //     32,768
    float* xd      = e2 + 32768;                                //     32,768
    float* xinA    = xd + 32768;                                //     32,768
    unsigned short* ctx_bf = (unsigned short*)(xinA + 32768);   //  8,388,608 f-slots
    unsigned short* Wt     = (unsigned short*)(xinA + 32768 + 8388608);  // 1,048,576
    unsigned short* h_bf   = (unsigned short*)(xinA + 32768 + 9437184);  //   131,072 (2 bufs)
    float* c_f     = xinA + 32768 + 9568256;                    //    131,072
    // aliases on ctx_all (consumed strictly before ctx_all is written):
    float* z1T    = ctx_all;
    float* ep_tmp = ctx_all;

    // ---- one-time tables & conversions
    k_h0build<<<dim3(NS_ * D_ / 1024), 256, 0, stream>>>(W0, b0, h0T);
    k_gemm128<<<dim3(G_ / 128, NS_ / 128), 256, 0, stream>>>(h0T, D_, W1, G_, z1T, G_, D_);
    k_gates1<<<dim3(NS_ * D_ / 1024), 256, 0, stream>>>(z1T, b1, h1c1T);
    k_gemm128<<<dim3(A_ / 128, NS_ / 128), 256, 0, stream>>>(h1c1T, 2 * D_, Wq, A_, qT, A_, 2 * D_);
    k_gemm128<<<dim3(G_ / 128, NS_ / 128), 256, 0, stream>>>(h1c1T, 2 * D_, Wf, G_, zhT, G_, D_);
    k_gemm128<<<dim3(A_ / 128, (B_ * T_) / 128), 256, 0, stream>>>(enc, U_, Wk, A_, ep_tmp, A_, U_);
    k_cvt_bf16<<<dim3(8192), 256, 0, stream>>>(ep_tmp, ep_bf);
    k_cvt_bf16<<<dim3(8192), 256, 0, stream>>>(enc, enc_bf);
    k_xd<<<dim3(B_ * T_ / 256), 256, 0, stream>>>(inputs, Wd, bd, xd);
    k_e2<<<dim3(B_ * T_ / 4), 256, 0, stream>>>(enc, Wd + F_, e2);
    k_wt<<<dim3(32, 16), 256, 0, stream>>>(Uf, Wf, Wt);

    hipMemsetAsync(h_bf, 0, (size_t)B_ * D_ * sizeof(unsigned short), stream);  // buffer 0
    hipMemsetAsync(c_f, 0, (size_t)B_ * D_ * sizeof(float), stream);

    // ---- decoder: score table -> scalar chain -> all contexts
    k_stab<<<dim3(B_ * 64), 256, 0, stream>>>(qT, ep_bf, v_att, s_tab);
    k_chain<<<dim3(B_), 64, 0, stream>>>(s_tab, e2, xd, xinA);
    k_ctx_all<<<dim3(B_ * 8), 512, 0, stream>>>(qT, xinA, v_att, ep_bf, enc_bf, ctx_all);
    k_cvt_bf16<<<dim3(8192), 256, 0, stream>>>(ctx_all, ctx_bf);

    // ---- final LSTM: 128 fused MFMA steps (h double-buffered)
    for (int j = 0; j < T_; ++j) {
        const unsigned short* hin = h_bf + (size_t)(j & 1) * (B_ * D_);
        unsigned short* hout = h_bf + (size_t)((j + 1) & 1) * (B_ * D_);
        k_frec<<<dim3(32, 8), 256, 0, stream>>>(hin, hout, ctx_bf, Wt, zhT, xinA,
                                                bf, c_f, out, j);
    }
}

// Round 7
// 2272.142 us; speedup vs baseline: 9.1548x; 1.9580x over previous
//
#include <hip/hip_runtime.h>

// Problem constants
constexpr int B_ = 256;
constexpr int T_ = 128;
constexpr int F_ = 32;
constexpr int U_ = 512;   // U_ENC
constexpr int D_ = 512;
constexpr int A_ = 512;
constexpr int G_ = 2048;  // 4*D

// xin lookup tables: qT/zhT fine grid; s_tab coarse grid
constexpr int   NS_   = 2048;
constexpr float LO_   = -8.0f;
constexpr float IDT_  = 128.0f;   // spacing 1/128 over [-8,8)
constexpr int   KS_   = 128;
constexpr float LOS_  = -8.0f;
constexpr float IDTS_ = 8.0f;     // spacing 1/8; s-grid k <-> qT row 16k

typedef short bf16x8 __attribute__((ext_vector_type(8)));
typedef _Float16 f16x8 __attribute__((ext_vector_type(8)));
typedef float f32x4 __attribute__((ext_vector_type(4)));

// fast transcendentals: v_exp_f32 + v_rcp_f32 (no IEEE divide sequences)
__device__ __forceinline__ float sigf(float x) {
    float t = __builtin_amdgcn_exp2f(-1.44269504089f * x);
    return __builtin_amdgcn_rcpf(1.0f + t);
}
__device__ __forceinline__ float tanh_fast(float x) {
    float t = __builtin_amdgcn_exp2f(-2.88539008178f * x);
    return 2.0f * __builtin_amdgcn_rcpf(1.0f + t) - 1.0f;
}
__device__ __forceinline__ float bflo(unsigned int u) { return __uint_as_float(u << 16); }
__device__ __forceinline__ float bfhi(unsigned int u) { return __uint_as_float(u & 0xffff0000u); }
__device__ __forceinline__ unsigned short f2bf(float x) {
    unsigned int u = __float_as_uint(x);
    u = (u + 0x7fffu + ((u >> 16) & 1u)) >> 16;
    return (unsigned short)u;
}

// ---------------------------------------------------------------------------
// Generic f32 GEMM: C[M,N] = A[M,K]@B[K,N].  BM=BN=128, BK=16, TM=TN=8.
__global__ __launch_bounds__(256) void k_gemm128(
    const float* __restrict__ A, int lda,
    const float* __restrict__ Bm, int ldb,
    float* __restrict__ C, int ldc, int K) {
    constexpr int BK = 16;
    __shared__ float As[BK][132];
    __shared__ float Bs[BK][128];
    const int tid = threadIdx.x;
    const int tx = tid & 15, ty = tid >> 4;
    const int m0 = blockIdx.y * 128, n0 = blockIdx.x * 128;
    const int am0 = tid >> 2,          ak40 = (tid & 3) * 4;
    const int am1 = (256 + tid) >> 2,  ak41 = ((256 + tid) & 3) * 4;
    const int bk0 = tid >> 5,          bn40 = (tid & 31) * 4;
    const int bk1 = (256 + tid) >> 5,  bn41 = ((256 + tid) & 31) * 4;
    const float* a0p = A + (size_t)(m0 + am0) * lda + ak40;
    const float* a1p = A + (size_t)(m0 + am1) * lda + ak41;
    const float* b0p = Bm + (size_t)bk0 * ldb + n0 + bn40;
    const float* b1p = Bm + (size_t)bk1 * ldb + n0 + bn41;
    float4 ar0 = *(const float4*)(a0p);
    float4 ar1 = *(const float4*)(a1p);
    float4 br0 = *(const float4*)(b0p);
    float4 br1 = *(const float4*)(b1p);
    float acc[8][8] = {};
    for (int k0 = 0; k0 < K; k0 += BK) {
        __syncthreads();
        As[ak40 + 0][am0] = ar0.x; As[ak40 + 1][am0] = ar0.y;
        As[ak40 + 2][am0] = ar0.z; As[ak40 + 3][am0] = ar0.w;
        As[ak41 + 0][am1] = ar1.x; As[ak41 + 1][am1] = ar1.y;
        As[ak41 + 2][am1] = ar1.z; As[ak41 + 3][am1] = ar1.w;
        *(float4*)&Bs[bk0][bn40] = br0;
        *(float4*)&Bs[bk1][bn41] = br1;
        __syncthreads();
        if (k0 + BK < K) {
            ar0 = *(const float4*)(a0p + k0 + BK);
            ar1 = *(const float4*)(a1p + k0 + BK);
            br0 = *(const float4*)(b0p + (size_t)(k0 + BK) * ldb);
            br1 = *(const float4*)(b1p + (size_t)(k0 + BK) * ldb);
        }
        #pragma unroll
        for (int kk = 0; kk < BK; ++kk) {
            float a[8], b[8];
            *(float4*)&a[0] = *(const float4*)&As[kk][ty * 8];
            *(float4*)&a[4] = *(const float4*)&As[kk][ty * 8 + 4];
            *(float4*)&b[0] = *(const float4*)&Bs[kk][tx * 8];
            *(float4*)&b[4] = *(const float4*)&Bs[kk][tx * 8 + 4];
            #pragma unroll
            for (int im = 0; im < 8; ++im)
                #pragma unroll
                for (int in = 0; in < 8; ++in)
                    acc[im][in] += a[im] * b[in];
        }
    }
    #pragma unroll
    for (int im = 0; im < 8; ++im) {
        float* crow = C + (size_t)(m0 + ty * 8 + im) * ldc + n0 + tx * 8;
        *(float4*)(crow)     = make_float4(acc[im][0], acc[im][1], acc[im][2], acc[im][3]);
        *(float4*)(crow + 4) = make_float4(acc[im][4], acc[im][5], acc[im][6], acc[im][7]);
    }
}

// ---------------------------------------------------------------------------
__global__ __launch_bounds__(256) void k_h0build(
    const float* __restrict__ W0, const float* __restrict__ b0,
    float* __restrict__ h0T) {
    int idx4 = blockIdx.x * 256 + threadIdx.x;
    int s = idx4 >> 7, kq = (idx4 & 127) * 4;
    float sv = LO_ + (float)s * (1.0f / IDT_);
    float4 o;
    float* po = &o.x;
    #pragma unroll
    for (int jj = 0; jj < 4; ++jj) {
        int k = kq + jj;
        float zi = sv * W0[k] + b0[k];
        float zg = sv * W0[1024 + k] + b0[1024 + k];
        float zo = sv * W0[1536 + k] + b0[1536 + k];
        float c0 = sigf(zi) * tanh_fast(zg);
        po[jj] = sigf(zo) * tanh_fast(c0);
    }
    *(float4*)(h0T + (size_t)s * D_ + kq) = o;
}

__global__ __launch_bounds__(256) void k_gates1(
    const float* __restrict__ z1T, const float* __restrict__ b1,
    float* __restrict__ h1c1T) {
    int idx4 = blockIdx.x * 256 + threadIdx.x;
    int s = idx4 >> 7, dq = (idx4 & 127) * 4;
    const float* z = z1T + (size_t)s * G_;
    float4 hv, cv;
    float* ph = &hv.x; float* pc = &cv.x;
    #pragma unroll
    for (int jj = 0; jj < 4; ++jj) {
        int d = dq + jj;
        float zi = z[d] + b1[d];
        float zg = z[1024 + d] + b1[1024 + d];
        float zo = z[1536 + d] + b1[1536 + d];
        float c1 = sigf(zi) * tanh_fast(zg);
        pc[jj] = c1;
        ph[jj] = sigf(zo) * tanh_fast(c1);
    }
    *(float4*)(h1c1T + (size_t)s * (2 * D_) + dq) = hv;
    *(float4*)(h1c1T + (size_t)s * (2 * D_) + D_ + dq) = cv;
}

__global__ __launch_bounds__(256) void k_xd(
    const float* __restrict__ inp, const float* __restrict__ Wd,
    const float* __restrict__ bd, float* __restrict__ xd) {
    int id = blockIdx.x * 256 + threadIdx.x;
    const float* row = inp + (size_t)id * F_;
    float s = 0.f;
    #pragma unroll
    for (int f = 0; f < F_; ++f) s += row[f] * Wd[f];
    xd[id] = s + bd[0];
}

// f32 -> bf16 (RNE), 8 elems/thread
__global__ __launch_bounds__(256) void k_cvt_bf16(
    const float* __restrict__ src, unsigned short* __restrict__ dst) {
    size_t i = ((size_t)blockIdx.x * 256 + threadIdx.x) * 8;
    float4 a = *(const float4*)(src + i);
    float4 b = *(const float4*)(src + i + 4);
    float v[8] = {a.x, a.y, a.z, a.w, b.x, b.y, b.z, b.w};
    unsigned int pk[4];
    #pragma unroll
    for (int j = 0; j < 4; ++j) {
        unsigned int u0 = (unsigned int)f2bf(v[2 * j]);
        unsigned int u1 = (unsigned int)f2bf(v[2 * j + 1]);
        pk[j] = u0 | (u1 << 16);
    }
    *(uint4*)(dst + i) = make_uint4(pk[0], pk[1], pk[2], pk[3]);
}

// e2[row] = enc[row,:] . Wd2
__global__ __launch_bounds__(256) void k_e2(
    const float* __restrict__ enc, const float* __restrict__ Wd2,
    float* __restrict__ e2) {
    const int row = blockIdx.x * 4 + (threadIdx.x >> 6);
    const int lane = threadIdx.x & 63;
    const float* p = enc + (size_t)row * U_ + lane * 8;
    float4 a = *(const float4*)p;
    float4 c = *(const float4*)(p + 4);
    const float* w = Wd2 + lane * 8;
    float4 wa = *(const float4*)w;
    float4 wc = *(const float4*)(w + 4);
    float s = a.x*wa.x + a.y*wa.y + a.z*wa.z + a.w*wa.w
            + c.x*wc.x + c.y*wc.y + c.z*wc.z + c.w*wc.w;
    #pragma unroll
    for (int off = 32; off; off >>= 1) s += __shfl_xor(s, off);
    if (lane == 0) e2[row] = s;
}

// WkT[a][u] = bf16(Wk[u][a])  (512x512)
__global__ __launch_bounds__(256) void k_wkT(
    const float* __restrict__ Wk, unsigned short* __restrict__ WkT) {
    int idx = blockIdx.x * 256 + threadIdx.x;   // 65536 items
    int a = idx >> 7, u0 = (idx & 127) * 4;
    unsigned int lo = (unsigned int)f2bf(Wk[(size_t)(u0 + 0) * A_ + a])
                    | ((unsigned int)f2bf(Wk[(size_t)(u0 + 1) * A_ + a]) << 16);
    unsigned int hi = (unsigned int)f2bf(Wk[(size_t)(u0 + 2) * A_ + a])
                    | ((unsigned int)f2bf(Wk[(size_t)(u0 + 3) * A_ + a]) << 16);
    *(uint2*)(WkT + (size_t)a * U_ + u0) = make_uint2(lo, hi);
}

// encT[b][u][tp] = f16(enc[b][tp][u])
__global__ __launch_bounds__(256) void k_encT(
    const float* __restrict__ enc, _Float16* __restrict__ encT) {
    __shared__ _Float16 tile[128][136];
    const int b = blockIdx.x >> 2;
    const int u0 = (blockIdx.x & 3) * 128;
    const int tid = threadIdx.x;
    #pragma unroll
    for (int p = 0; p < 16; ++p) {
        int i = p * 256 + tid;
        int tp = i >> 5, u4 = (i & 31) * 4;
        float4 v = *(const float4*)(enc + ((size_t)(b * T_ + tp)) * U_ + u0 + u4);
        tile[u4 + 0][tp] = (_Float16)v.x;
        tile[u4 + 1][tp] = (_Float16)v.y;
        tile[u4 + 2][tp] = (_Float16)v.z;
        tile[u4 + 3][tp] = (_Float16)v.w;
    }
    __syncthreads();
    #pragma unroll
    for (int p = 0; p < 8; ++p) {
        int i = p * 256 + tid;
        int u = i >> 4, t8 = (i & 15) * 8;
        uint4 v = *(const uint4*)&tile[u][t8];
        *(uint4*)(encT + ((size_t)(b * U_ + u0 + u)) * T_ + t8) = v;
    }
}

// ---------------------------------------------------------------------------
// ep MFMA GEMM: ep_bf[r][a] = enc_bf[r][:] . WkT[a][:]  (M=32768,N=512,K=512)
// grid (4 n-tiles, 256 m-tiles), 4 waves (2m x 2n), 64x64 per wave, no LDS.
__global__ __launch_bounds__(256) void k_epmm(
    const unsigned short* __restrict__ enc_bf,
    const unsigned short* __restrict__ WkT,
    unsigned short* __restrict__ ep_bf) {
    const int n0 = blockIdx.x * 128;
    const int m0 = blockIdx.y * 128;
    const int lane = threadIdx.x & 63, wave = threadIdx.x >> 6;
    const int wm = wave >> 1, wn = wave & 1;
    const int frow = lane & 15, koct = (lane >> 4) * 8;
    const unsigned short* Ab = enc_bf + ((size_t)(m0 + wm * 64 + frow)) * U_ + koct;
    const unsigned short* Bb = WkT + ((size_t)(n0 + wn * 64 + frow)) * U_ + koct;
    f32x4 acc[4][4] = {};
    for (int ks = 0; ks < 16; ++ks) {
        bf16x8 a[4], bb[4];
        #pragma unroll
        for (int m = 0; m < 4; ++m) a[m] = *(const bf16x8*)(Ab + (size_t)m * 16 * U_ + ks * 32);
        #pragma unroll
        for (int n = 0; n < 4; ++n) bb[n] = *(const bf16x8*)(Bb + (size_t)n * 16 * U_ + ks * 32);
        #pragma unroll
        for (int m = 0; m < 4; ++m)
            #pragma unroll
            for (int n = 0; n < 4; ++n)
                acc[m][n] = __builtin_amdgcn_mfma_f32_16x16x32_bf16(a[m], bb[n], acc[m][n], 0, 0, 0);
    }
    #pragma unroll
    for (int m = 0; m < 4; ++m)
        #pragma unroll
        for (int n = 0; n < 4; ++n)
            #pragma unroll
            for (int reg = 0; reg < 4; ++reg) {
                int r = m0 + wm * 64 + m * 16 + (lane >> 4) * 4 + reg;
                int a = n0 + wn * 64 + n * 16 + (lane & 15);
                ep_bf[(size_t)r * A_ + a] = f2bf(acc[m][n][reg]);
            }
}

// ---------------------------------------------------------------------------
// Score table: s_tab[b][tp][k] = sum_a tanh(qT[16k][a] + ep[b,tp][a]) * v[a].
// Block = (b, 8 tps); wave handles 32 k's; lane owns 8 a-elems.
__global__ __launch_bounds__(256) void k_stab(
    const float* __restrict__ qT, const unsigned short* __restrict__ ep_bf,
    const float* __restrict__ v_att, float* __restrict__ s_tab) {
    const int b = blockIdx.x >> 4;
    const int tp0 = (blockIdx.x & 15) * 8;
    const int lane = threadIdx.x & 63, wave = threadIdx.x >> 6;
    float e8[8][8];
    #pragma unroll
    for (int r = 0; r < 8; ++r) {
        uint4 ev = *(const uint4*)(ep_bf + ((size_t)(b * T_ + tp0 + r)) * A_ + lane * 8);
        e8[r][0] = bflo(ev.x); e8[r][1] = bfhi(ev.x);
        e8[r][2] = bflo(ev.y); e8[r][3] = bfhi(ev.y);
        e8[r][4] = bflo(ev.z); e8[r][5] = bfhi(ev.z);
        e8[r][6] = bflo(ev.w); e8[r][7] = bfhi(ev.w);
    }
    float v8[8];
    *(float4*)&v8[0] = *(const float4*)(v_att + lane * 8);
    *(float4*)&v8[4] = *(const float4*)(v_att + lane * 8 + 4);
    for (int kk = 0; kk < 32; ++kk) {
        const int k = wave * 32 + kk;
        const float* q = qT + (size_t)k * 16 * A_ + lane * 8;
        float q8[8];
        *(float4*)&q8[0] = *(const float4*)(q);
        *(float4*)&q8[4] = *(const float4*)(q + 4);
        float s[8] = {};
        #pragma unroll
        for (int r = 0; r < 8; ++r)
            #pragma unroll
            for (int j = 0; j < 8; ++j)
                s[r] += tanh_fast(q8[j] + e8[r][j]) * v8[j];
        #pragma unroll
        for (int r = 0; r < 8; ++r) {
            float x = s[r];
            #pragma unroll
            for (int off = 32; off; off >>= 1) x += __shfl_xor(x, off);
            if (lane == 0) s_tab[((size_t)(b * T_ + tp0 + r)) * KS_ + k] = x;
        }
    }
}

// ---------------------------------------------------------------------------
// Full xin recurrence + softmax weight output. 256 blocks (per b), 1 wave.
// Lane owns tp = 2*lane, 2*lane+1; writes w_h (f16 pair) per step.
__global__ __launch_bounds__(64) void k_chain(
    const float* __restrict__ s_tab, const float* __restrict__ e2,
    const float* __restrict__ xd, float* __restrict__ xinA,
    unsigned int* __restrict__ w_h32) {
    const int b = blockIdx.x;
    const int lane = threadIdx.x;
    const int tpA = 2 * lane, tpB = 2 * lane + 1;
    const float e20 = e2[b * T_ + tpA];
    const float e21 = e2[b * T_ + tpB];
    const float* st0 = s_tab + ((size_t)b * T_ + tpA) * KS_;
    const float* st1 = s_tab + ((size_t)b * T_ + tpB) * KS_;
    float xin = xd[b * T_];
    for (int t = 0; t < T_; ++t) {
        if (lane == 0) xinA[t * B_ + b] = xin;
        float u = (xin - LOS_) * IDTS_;
        u = fminf(fmaxf(u, 0.0f), (float)KS_ - 1.001f);
        int k0 = (int)u; float fr = u - (float)k0;
        float a0 = st0[k0], a1 = st0[k0 + 1];
        float c0 = st1[k0], c1 = st1[k0 + 1];
        float s0 = a0 + fr * (a1 - a0);
        float s1 = c0 + fr * (c1 - c0);
        float m = fmaxf(s0, s1);
        #pragma unroll
        for (int off = 32; off; off >>= 1) m = fmaxf(m, __shfl_xor(m, off));
        float ex0 = __builtin_amdgcn_exp2f(1.44269504089f * (s0 - m));
        float ex1 = __builtin_amdgcn_exp2f(1.44269504089f * (s1 - m));
        float num = ex0 * e20 + ex1 * e21;
        float den = ex0 + ex1;
        #pragma unroll
        for (int off = 32; off; off >>= 1) {
            num += __shfl_xor(num, off);
            den += __shfl_xor(den, off);
        }
        float rdn = __builtin_amdgcn_rcpf(den);
        union { _Float16 h[2]; unsigned int u32; } cv;
        cv.h[0] = (_Float16)(ex0 * rdn);
        cv.h[1] = (_Float16)(ex1 * rdn);
        w_h32[((size_t)b * T_ + t) * 64 + lane] = cv.u32;
        if (t + 1 < T_) xin = xd[b * T_ + t + 1] + num * rdn;
    }
}

// ---------------------------------------------------------------------------
// ctx MFMA GEMM (f16): ctx[t][u] = w[t][:] . encT[u][:] per b; K = T' = 128.
// grid (b*4): 4 u-slices of 128. 4 waves (2t x 2u), 64x64 per wave, no LDS.
// Writes ctx_bf[t][b][u] (bf16).
__global__ __launch_bounds__(256) void k_ctxmm(
    const _Float16* __restrict__ w_h, const _Float16* __restrict__ encT,
    unsigned short* __restrict__ ctx_bf) {
    const int b = blockIdx.x >> 2;
    const int n0 = (blockIdx.x & 3) * 128;
    const int lane = threadIdx.x & 63, wave = threadIdx.x >> 6;
    const int wm = wave >> 1, wn = wave & 1;
    const int frow = lane & 15, koct = (lane >> 4) * 8;
    const _Float16* Ab = w_h + ((size_t)b * T_ + wm * 64 + frow) * T_ + koct;
    const _Float16* Bb = encT + ((size_t)(b * U_ + n0 + wn * 64 + frow)) * T_ + koct;
    f32x4 acc[4][4] = {};
    #pragma unroll
    for (int ks = 0; ks < 4; ++ks) {
        f16x8 a[4], bb[4];
        #pragma unroll
        for (int m = 0; m < 4; ++m) a[m] = *(const f16x8*)(Ab + (size_t)m * 16 * T_ + ks * 32);
        #pragma unroll
        for (int n = 0; n < 4; ++n) bb[n] = *(const f16x8*)(Bb + (size_t)n * 16 * T_ + ks * 32);
        #pragma unroll
        for (int m = 0; m < 4; ++m)
            #pragma unroll
            for (int n = 0; n < 4; ++n)
                acc[m][n] = __builtin_amdgcn_mfma_f32_16x16x32_f16(a[m], bb[n], acc[m][n], 0, 0, 0);
    }
    #pragma unroll
    for (int m = 0; m < 4; ++m)
        #pragma unroll
        for (int n = 0; n < 4; ++n)
            #pragma unroll
            for (int reg = 0; reg < 4; ++reg) {
                int t = wm * 64 + m * 16 + (lane >> 4) * 4 + reg;
                int u = n0 + wn * 64 + n * 16 + (lane & 15);
                ctx_bf[((size_t)t * B_ + b) * U_ + u] = f2bf(acc[m][n][reg]);
            }
}

// ---------------------------------------------------------------------------
// Build Wt[2048 cols][1024 k] bf16: Wt[c][k] = (k<512 ? Uf[k][c] : Wf[k][c]).
__global__ __launch_bounds__(256) void k_wt(
    const float* __restrict__ Uf, const float* __restrict__ Wf,
    unsigned short* __restrict__ Wt) {
    __shared__ unsigned short tile[64][72];
    const int c0 = blockIdx.x * 64, k0 = blockIdx.y * 64;
    const int tid = threadIdx.x;
    const float* src = (k0 < 512) ? Uf : Wf;
    #pragma unroll
    for (int p = 0; p < 4; ++p) {
        int kk = (tid >> 4) + p * 16;
        int cc4 = (tid & 15) * 4;
        float4 v = *(const float4*)(src + (size_t)(k0 + kk) * G_ + c0 + cc4);
        tile[cc4 + 0][kk] = f2bf(v.x);
        tile[cc4 + 1][kk] = f2bf(v.y);
        tile[cc4 + 2][kk] = f2bf(v.z);
        tile[cc4 + 3][kk] = f2bf(v.w);
    }
    __syncthreads();
    #pragma unroll
    for (int p = 0; p < 4; ++p) {
        int cc = (tid >> 4) + p * 16;
        int k4 = (tid & 15) * 4;
        uint2 v = *(const uint2*)&tile[cc][k4];
        *(uint2*)(Wt + (size_t)(c0 + cc) * 1024 + k0 + k4) = v;
    }
}

// ---------------------------------------------------------------------------
// Final LSTM step, fully fused, MFMA (unchanged structure from round 6).
__global__ __launch_bounds__(256) void k_frec(
    const unsigned short* __restrict__ hin, unsigned short* __restrict__ hout,
    const unsigned short* __restrict__ ctx_bf, const unsigned short* __restrict__ Wt,
    const float* __restrict__ zhT, const float* __restrict__ xinA,
    const float* __restrict__ bfv, float* __restrict__ c_f,
    float* __restrict__ out, int j) {
    __shared__ unsigned short As[32 * 72];
    __shared__ unsigned short Bs[64 * 72];
    __shared__ float zs[32 * 68];
    const int tid = threadIdx.x;
    const int lane = tid & 63, wave = tid >> 6;
    const int wr = wave >> 1, wc = wave & 1;
    const int d0 = blockIdx.x * 16;
    const int r0 = blockIdx.y * 32;
    const int ar_ = tid >> 3, aseg = tid & 7;
    const int ai = r0 + ar_;
    const size_t a_lo = (size_t)ai * 512 + aseg * 8;
    const size_t a_hi = ((size_t)(ai >> 1) * B_ + ((ai & 1) << 7) + j) * 512 + aseg * 8;
    const int bcA = tid >> 3, bcB = 32 + (tid >> 3), bseg = tid & 7;
    const size_t boffA = (size_t)(((bcA >> 4) << 9) + d0 + (bcA & 15)) * 1024 + bseg * 8;
    const size_t boffB = (size_t)(((bcB >> 4) << 9) + d0 + (bcB & 15)) * 1024 + bseg * 8;
    uint4 av = *(const uint4*)(hin + a_lo);
    uint4 bv0 = *(const uint4*)(Wt + boffA);
    uint4 bv1 = *(const uint4*)(Wt + boffB);
    f32x4 acc0 = {0.f, 0.f, 0.f, 0.f};
    f32x4 acc1 = {0.f, 0.f, 0.f, 0.f};
    const int arow = 16 * wr + (lane & 15);
    const int brow0 = 32 * wc + (lane & 15);
    const int brow1 = brow0 + 16;
    const int koct = (lane >> 4) * 8;
    for (int kc = 0; kc < 16; ++kc) {
        __syncthreads();
        *(uint4*)&As[ar_ * 72 + aseg * 8] = av;
        *(uint4*)&Bs[bcA * 72 + bseg * 8] = bv0;
        *(uint4*)&Bs[bcB * 72 + bseg * 8] = bv1;
        __syncthreads();
        if (kc < 15) {
            const int k0 = (kc + 1) * 64;
            av = (k0 < 512) ? *(const uint4*)(hin + a_lo + k0)
                            : *(const uint4*)(ctx_bf + a_hi + (k0 - 512));
            bv0 = *(const uint4*)(Wt + boffA + k0);
            bv1 = *(const uint4*)(Wt + boffB + k0);
        }
        #pragma unroll
        for (int ks = 0; ks < 2; ++ks) {
            const int kb = ks * 32 + koct;
            bf16x8 af = *(const bf16x8*)&As[arow * 72 + kb];
            bf16x8 b0 = *(const bf16x8*)&Bs[brow0 * 72 + kb];
            bf16x8 b1 = *(const bf16x8*)&Bs[brow1 * 72 + kb];
            acc0 = __builtin_amdgcn_mfma_f32_16x16x32_bf16(af, b0, acc0, 0, 0, 0);
            acc1 = __builtin_amdgcn_mfma_f32_16x16x32_bf16(af, b1, acc1, 0, 0, 0);
        }
    }
    {
        const int srow = 16 * wr + (lane >> 4) * 4;
        const int scol = 32 * wc + (lane & 15);
        #pragma unroll
        for (int reg = 0; reg < 4; ++reg) {
            zs[(srow + reg) * 68 + scol] = acc0[reg];
            zs[(srow + reg) * 68 + scol + 16] = acc1[reg];
        }
    }
    __syncthreads();
    #pragma unroll
    for (int p = 0; p < 2; ++p) {
        const int it = p * 256 + tid;
        const int r = it >> 4, dd = it & 15;
        const int i = r0 + r, d = d0 + dd;
        float zg4[4];
        zg4[0] = zs[r * 68 + dd];
        zg4[1] = zs[r * 68 + 16 + dd];
        zg4[2] = zs[r * 68 + 32 + dd];
        zg4[3] = zs[r * 68 + 48 + dd];
        const float xv = xinA[(i >> 1) * B_ + ((i & 1) << 7) + j];
        float u = (xv - LO_) * IDT_;
        u = fminf(fmaxf(u, 0.0f), (float)NS_ - 1.001f);
        const int i0 = (int)u;
        const float fr = u - (float)i0;
        const float* zh0 = zhT + (size_t)i0 * G_;
        const float* zh1 = zh0 + G_;
        #pragma unroll
        for (int g = 0; g < 4; ++g) {
            const int col = g * 512 + d;
            const float lo = zh0[col];
            zg4[g] += lo + fr * (zh1[col] - lo) + bfv[col];
        }
        const float co = c_f[(size_t)i * D_ + d];
        const float cn = sigf(zg4[1]) * co + sigf(zg4[0]) * tanh_fast(zg4[2]);
        const float hn = sigf(zg4[3]) * tanh_fast(cn);
        c_f[(size_t)i * D_ + d] = cn;
        hout[(size_t)i * D_ + d] = f2bf(hn);
        out[((size_t)i * T_ + j) * D_ + d] = hn;
    }
}

// ---------------------------------------------------------------------------
extern "C" void kernel_launch(void* const* d_in, const int* in_sizes, int n_in,
                              void* d_out, int out_size, void* d_ws, size_t ws_size,
                              hipStream_t stream) {
    const float* inputs = (const float*)d_in[0];
    const float* enc    = (const float*)d_in[1];
    const float* Wd     = (const float*)d_in[2];
    const float* bd     = (const float*)d_in[3];
    const float* W0     = (const float*)d_in[4];
    const float* b0     = (const float*)d_in[6];
    const float* W1     = (const float*)d_in[7];
    const float* b1     = (const float*)d_in[9];
    const float* Wq     = (const float*)d_in[10];
    const float* Wk     = (const float*)d_in[11];
    const float* v_att  = (const float*)d_in[12];
    const float* Wf     = (const float*)d_in[13];
    const float* Uf     = (const float*)d_in[14];
    const float* bf     = (const float*)d_in[15];
    float* out = (float*)d_out;

    float* ws = (float*)d_ws;
    // layout in f32 slots
    unsigned short* enc_bf = (unsigned short*)(ws);                    // 8,388,608 slots
    unsigned short* ep_bf  = (unsigned short*)(ws + 8388608);          // 8,388,608
    _Float16*       encT_h = (_Float16*)(ws + 16777216);               // 8,388,608
    unsigned short* ctx_bf = (unsigned short*)(ws + 25165824);         // 8,388,608
    float* s_tab   = ws + 33554432;                                    // 4,194,304
    _Float16* w_h  = (_Float16*)(ws + 37748736);                       // 2,097,152 slots
    float* qT      = ws + 39845888;                                    // 1,048,576
    float* zhT     = ws + 40894464;                                    // 4,194,304
    float* h0T     = ws + 45088768;                                    // 1,048,576
    float* h1c1T   = ws + 46137344;                                    // 2,097,152
    unsigned short* Wt  = (unsigned short*)(ws + 48234496);            // 1,048,576 slots
    unsigned short* WkT = (unsigned short*)(ws + 49283072);            //   131,072 slots
    float* e2      = ws + 49414144;                                    //    32,768
    float* xd      = ws + 49446912;                                    //    32,768
    float* xinA    = ws + 49479680;                                    //    32,768
    unsigned short* h_bf = (unsigned short*)(ws + 49512448);           //   131,072 slots (2 bufs)
    float* c_f     = ws + 49643520;                                    //   131,072
    // z1T aliases ctx_bf region (dead before k_ctxmm writes ctx_bf)
    float* z1T = (float*)ctx_bf;

    // ---- one-time tables & conversions
    k_h0build<<<dim3(NS_ * D_ / 1024), 256, 0, stream>>>(W0, b0, h0T);
    k_gemm128<<<dim3(G_ / 128, NS_ / 128), 256, 0, stream>>>(h0T, D_, W1, G_, z1T, G_, D_);
    k_gates1<<<dim3(NS_ * D_ / 1024), 256, 0, stream>>>(z1T, b1, h1c1T);
    k_gemm128<<<dim3(A_ / 128, NS_ / 128), 256, 0, stream>>>(h1c1T, 2 * D_, Wq, A_, qT, A_, 2 * D_);
    k_gemm128<<<dim3(G_ / 128, NS_ / 128), 256, 0, stream>>>(h1c1T, 2 * D_, Wf, G_, zhT, G_, D_);
    k_cvt_bf16<<<dim3(8192), 256, 0, stream>>>(enc, enc_bf);
    k_wkT<<<dim3(256), 256, 0, stream>>>(Wk, WkT);
    k_epmm<<<dim3(4, 256), 256, 0, stream>>>(enc_bf, WkT, ep_bf);
    k_encT<<<dim3(B_ * 4), 256, 0, stream>>>(enc, encT_h);
    k_xd<<<dim3(B_ * T_ / 256), 256, 0, stream>>>(inputs, Wd, bd, xd);
    k_e2<<<dim3(B_ * T_ / 4), 256, 0, stream>>>(enc, Wd + F_, e2);
    k_wt<<<dim3(32, 16), 256, 0, stream>>>(Uf, Wf, Wt);

    hipMemsetAsync(h_bf, 0, (size_t)B_ * D_ * sizeof(unsigned short), stream);
    hipMemsetAsync(c_f, 0, (size_t)B_ * D_ * sizeof(float), stream);

    // ---- decoder: score table -> scalar chain (+weights) -> ctx GEMM
    k_stab<<<dim3(B_ * 16), 256, 0, stream>>>(qT, ep_bf, v_att, s_tab);
    k_chain<<<dim3(B_), 64, 0, stream>>>(s_tab, e2, xd, xinA, (unsigned int*)w_h);
    k_ctxmm<<<dim3(B_ * 4), 256, 0, stream>>>(w_h, encT_h, ctx_bf);

    // ---- final LSTM: 128 fused MFMA steps (h double-buffered)
    for (int j = 0; j < T_; ++j) {
        const unsigned short* hin = h_bf + (size_t)(j & 1) * (B_ * D_);
        unsigned short* hout = h_bf + (size_t)((j + 1) & 1) * (B_ * D_);
        k_frec<<<dim3(32, 8), 256, 0, stream>>>(hin, hout, ctx_bf, Wt, zhT, xinA,
                                                bf, c_f, out, j);
    }
}